// Round 5
// baseline (3348.755 us; speedup 1.0000x reference)
//
#include <hip/hip_runtime.h>
#include <math.h>

#define NUM_CODES 8192
#define DIM 256
#define NROWS 32768            // 32 * 32 * 32
#define NELEM (NROWS * DIM)    // 8388608

// d_out layout (fp32 elements): loss | quantized | perplexity | indices
#define OUT_LOSS 0
#define OUT_Q 1
#define OUT_PERP (1 + NELEM)
#define OUT_IDX (2 + NELEM)

#define DELTA 1e-3f
#define CAND_CAP 16
#define NQBLK (NELEM / 1024)

// ---- fast-path ws layout (bytes) ----
#define WF_XT    0x0        // 32768*256 bf16 (16 MB)
#define WF_CB    0x1000000  // 8192*256 bf16 (4 MB)
#define WF_A2    0x1400000  // 32768 f32 (128 KB)
#define WF_DMIN  0x1420000  // 32768 u32 (128 KB)
#define WF_CNT   0x1440000  // 32768 u32 (128 KB)
#define WF_CAND  0x1460000  // 32768*16 u32 (2 MB)
#define WF_IDX   0x1660000  // 32768 i32 (128 KB)
#define WF_COUNTS 0x1680000 // 8192 i32 (32 KB)
#define WF_PART  0x1688000  // 8192 f64 (64 KB)
#define WF_END   0x1698000  // ~23.6 MB

// ---- legacy (R4-verified) ws layout ----
#define WL_A2 0
#define WL_IDX 0x20000
#define WL_KEYS 0x40000
#define WL_COUNTS 0x40000   // aliases keys (dead after merge)
#define WL_PART 0x48000

typedef __bf16 bf16x8 __attribute__((ext_vector_type(8)));
typedef float f32x4 __attribute__((ext_vector_type(4)));

__device__ __forceinline__ unsigned f2bf_rne(float x) {
  const unsigned u = __float_as_uint(x);
  return (u + 0x7FFFu + ((u >> 16) & 1u)) >> 16;
}

// =================== shared kernels (both paths) ===================

// A[n] = np.sum(flat[n]**2), exact numpy pairwise fp32 (verified R3/R4)
__global__ __launch_bounds__(256) void k_a2(const float* __restrict__ in,
                                            float* __restrict__ a2) {
  const int n = (blockIdx.x << 8) + threadIdx.x;
  const int b = n >> 10, hw = n & 1023;
  const float* p = in + (((size_t)b) << 18) + hw;
  float s[2];
#pragma unroll
  for (int h = 0; h < 2; ++h) {
    const int c0 = h << 7;
    float r[8];
#pragma unroll
    for (int j = 0; j < 8; ++j) {
      const float v = p[(size_t)(c0 + j) << 10];
      r[j] = __fmul_rn(v, v);
    }
    for (int i = 8; i < 128; i += 8) {
#pragma unroll
      for (int j = 0; j < 8; ++j) {
        const float v = p[(size_t)(c0 + i + j) << 10];
        r[j] = __fadd_rn(r[j], __fmul_rn(v, v));
      }
    }
    s[h] = __fadd_rn(__fadd_rn(__fadd_rn(r[0], r[1]), __fadd_rn(r[2], r[3])),
                     __fadd_rn(__fadd_rn(r[4], r[5]), __fadd_rn(r[6], r[7])));
  }
  a2[n] = __fadd_rn(s[0], s[1]);
}

__global__ __launch_bounds__(256) void k_quant(const float* __restrict__ in,
                                               const float* __restrict__ cbk,
                                               const int* __restrict__ idx,
                                               float* __restrict__ outq,
                                               double* __restrict__ partials) {
  const int tid = threadIdx.x;
  const int e = (blockIdx.x << 10) + (tid << 2);
  const int bc = e >> 10;
  const int hw = e & 1023;
  const int b = bc >> 8;
  const int c = bc & 255;
  const int nbase = (b << 10) + hw;
  const float4 x = *(const float4*)(in + e);
  const float xv[4] = {x.x, x.y, x.z, x.w};
  double ls = 0.0;
  float o[4];
#pragma unroll
  for (int j = 0; j < 4; ++j) {
    const int qi = idx[nbase + j];
    const float q = cbk[((size_t)qi << 8) + c];
    const float diff = q - xv[j];
    o[j] = xv[j] + diff;
    ls += (double)diff * (double)diff;
  }
  outq[e] = o[0];
  outq[e + 1] = o[1];
  outq[e + 2] = o[2];
  outq[e + 3] = o[3];
#pragma unroll
  for (int off = 32; off >= 1; off >>= 1) ls += __shfl_down(ls, off, 64);
  __shared__ double wsum[4];
  const int lane = tid & 63, wid = tid >> 6;
  if (lane == 0) wsum[wid] = ls;
  __syncthreads();
  if (tid == 0) partials[blockIdx.x] = wsum[0] + wsum[1] + wsum[2] + wsum[3];
}

__global__ __launch_bounds__(256) void k_counts(const int* __restrict__ idx,
                                                int* __restrict__ counts) {
  const int n = (blockIdx.x << 8) + threadIdx.x;
  atomicAdd(&counts[idx[n]], 1);
}

__global__ __launch_bounds__(256) void k_finalize(const double* __restrict__ partials,
                                                  const int* __restrict__ counts,
                                                  float* __restrict__ out_loss,
                                                  float* __restrict__ out_perp) {
  const int tid = threadIdx.x;
  double sl = 0.0, se = 0.0;
  for (int i = tid; i < NQBLK; i += 256) sl += partials[i];
  for (int k = tid; k < NUM_CODES; k += 256) {
    const double p = (double)counts[k] / 32768.0;
    se += p * log(p + 1e-10);
  }
#pragma unroll
  for (int off = 32; off >= 1; off >>= 1) {
    sl += __shfl_down(sl, off, 64);
    se += __shfl_down(se, off, 64);
  }
  __shared__ double sL[4], sE[4];
  const int lane = tid & 63, wid = tid >> 6;
  if (lane == 0) { sL[wid] = sl; sE[wid] = se; }
  __syncthreads();
  if (tid == 0) {
    const double L = sL[0] + sL[1] + sL[2] + sL[3];
    const double E = sE[0] + sE[1] + sE[2] + sE[3];
    const double m = L / (double)NELEM;
    *out_loss = (float)(m + 0.6 * m);
    *out_perp = (float)exp(-E);
  }
}

// =================== fast path ===================

// codebook fp32 [k][c] -> bf16 [k][c] (RNE)
__global__ __launch_bounds__(256) void k_cvt_cb(const float* __restrict__ cbk,
                                                unsigned short* __restrict__ cbb) {
  const int e = (((blockIdx.x << 8) + threadIdx.x) << 3);  // 8 elems
  const float4 a = *(const float4*)(cbk + e);
  const float4 b = *(const float4*)(cbk + e + 4);
  uint4 o;
  o.x = f2bf_rne(a.x) | (f2bf_rne(a.y) << 16);
  o.y = f2bf_rne(a.z) | (f2bf_rne(a.w) << 16);
  o.z = f2bf_rne(b.x) | (f2bf_rne(b.y) << 16);
  o.w = f2bf_rne(b.z) | (f2bf_rne(b.w) << 16);
  *(uint4*)(cbb + e) = o;
}

// x fp32 [b][c][hw] -> bf16 xt[n][c] (transpose via LDS), RNE
__global__ __launch_bounds__(256) void k_cvt_x(const float* __restrict__ in,
                                               unsigned short* __restrict__ xt) {
  __shared__ float t[64][65];
  const int tid = threadIdx.x;
  const int n0 = (blockIdx.x >> 2) << 6;
  const int c0 = (blockIdx.x & 3) << 6;
  const int b = n0 >> 10, hw0 = n0 & 1023;
#pragma unroll
  for (int i = 0; i < 4; ++i) {
    const int f = (i << 8) + tid;          // 0..1023
    const int cl = f >> 4;                 // 0..63
    const int h4 = (f & 15) << 2;          // 0..60
    const float4 v = *(const float4*)(in + (((size_t)(b * DIM + c0 + cl)) << 10) + hw0 + h4);
    t[cl][h4 + 0] = v.x;
    t[cl][h4 + 1] = v.y;
    t[cl][h4 + 2] = v.z;
    t[cl][h4 + 3] = v.w;
  }
  __syncthreads();
#pragma unroll
  for (int i = 0; i < 2; ++i) {
    const int f = (i << 8) + tid;          // 0..511
    const int nl = f >> 3;                 // 0..63
    const int c8 = (f & 7) << 3;           // 0..56
    uint4 o;
    o.x = f2bf_rne(t[c8 + 0][nl]) | (f2bf_rne(t[c8 + 1][nl]) << 16);
    o.y = f2bf_rne(t[c8 + 2][nl]) | (f2bf_rne(t[c8 + 3][nl]) << 16);
    o.z = f2bf_rne(t[c8 + 4][nl]) | (f2bf_rne(t[c8 + 5][nl]) << 16);
    o.w = f2bf_rne(t[c8 + 6][nl]) | (f2bf_rne(t[c8 + 7][nl]) << 16);
    *(uint4*)&xt[(((size_t)(n0 + nl)) << 8) + c0 + c8] = o;
  }
}

// bf16 MFMA screening GEMM: 128 rows x 128 codes per block, K=256 in 64-chunks.
// d~ = fl(1 - 2*G^). PASS 1: per-row global min (atomicMin on float bits).
// PASS 2: identical deterministic compute; collect codes with d~ < min + DELTA.
#define XS_STR 72
template <int PASS>
__global__ __launch_bounds__(256, 4) void k_screen(
    const unsigned short* __restrict__ xt, const unsigned short* __restrict__ cbb,
    unsigned* __restrict__ dmin, unsigned* __restrict__ cnt,
    unsigned* __restrict__ cand) {
  __shared__ __align__(16) unsigned short xs[128 * XS_STR];
  __shared__ __align__(16) unsigned short cs[128 * XS_STR];
  const int tid = threadIdx.x;
  const int lane = tid & 63;
  const int w = tid >> 6;
  const int wm = w >> 1, wn = w & 1;
  const int m0 = (blockIdx.x >> 6) << 7;   // row block
  const int n0 = (blockIdx.x & 63) << 7;   // code block
  const int quad = lane >> 4;
  const int l15 = lane & 15;

  f32x4 acc[4][4];
#pragma unroll
  for (int mt = 0; mt < 4; ++mt)
#pragma unroll
    for (int nt = 0; nt < 4; ++nt) acc[mt][nt] = (f32x4){0.f, 0.f, 0.f, 0.f};

  for (int ch0 = 0; ch0 < DIM; ch0 += 64) {
#pragma unroll
    for (int i = 0; i < 4; ++i) {
      const int f = (i << 8) + tid;
      const int row = f >> 3;
      const int k8 = (f & 7) << 3;
      *(uint4*)&xs[row * XS_STR + k8] = *(const uint4*)&xt[((m0 + row) << 8) + ch0 + k8];
      *(uint4*)&cs[row * XS_STR + k8] = *(const uint4*)&cbb[((n0 + row) << 8) + ch0 + k8];
    }
    __syncthreads();
#pragma unroll
    for (int ks = 0; ks < 2; ++ks) {
      bf16x8 af[4], bf_[4];
#pragma unroll
      for (int mt = 0; mt < 4; ++mt)
        af[mt] = *(const bf16x8*)&xs[((wm << 6) + (mt << 4) + l15) * XS_STR + (ks << 5) + (quad << 3)];
#pragma unroll
      for (int nt = 0; nt < 4; ++nt)
        bf_[nt] = *(const bf16x8*)&cs[((wn << 6) + (nt << 4) + l15) * XS_STR + (ks << 5) + (quad << 3)];
#pragma unroll
      for (int mt = 0; mt < 4; ++mt)
#pragma unroll
        for (int nt = 0; nt < 4; ++nt)
          acc[mt][nt] = __builtin_amdgcn_mfma_f32_16x16x32_bf16(af[mt], bf_[nt], acc[mt][nt], 0, 0, 0);
    }
    __syncthreads();
  }

  if (PASS == 1) {
#pragma unroll
    for (int mt = 0; mt < 4; ++mt)
#pragma unroll
      for (int reg = 0; reg < 4; ++reg) {
        float v = 3.402823466e+38f;
#pragma unroll
        for (int nt = 0; nt < 4; ++nt) {
          const float d = __fadd_rn(1.0f, __fmul_rn(-2.0f, acc[mt][nt][reg]));
          v = fminf(v, d);
        }
        v = fminf(v, __shfl_xor(v, 1, 64));
        v = fminf(v, __shfl_xor(v, 2, 64));
        v = fminf(v, __shfl_xor(v, 4, 64));
        v = fminf(v, __shfl_xor(v, 8, 64));
        if (l15 == 0) {
          const int row = m0 + (wm << 6) + (mt << 4) + (quad << 2) + reg;
          atomicMin(&dmin[row], __float_as_uint(v));
        }
      }
  } else {
#pragma unroll
    for (int mt = 0; mt < 4; ++mt) {
      const int rowb = m0 + (wm << 6) + (mt << 4) + (quad << 2);
      float thr[4];
#pragma unroll
      for (int reg = 0; reg < 4; ++reg)
        thr[reg] = __uint_as_float(dmin[rowb + reg]) + DELTA;
#pragma unroll
      for (int nt = 0; nt < 4; ++nt) {
        const int code = n0 + (wn << 6) + (nt << 4) + l15;
#pragma unroll
        for (int reg = 0; reg < 4; ++reg) {
          const float d = __fadd_rn(1.0f, __fmul_rn(-2.0f, acc[mt][nt][reg]));
          if (d < thr[reg]) {
            const unsigned pos = atomicAdd(&cnt[rowb + reg], 1u);
            if (pos < CAND_CAP) cand[((rowb + reg) << 4) + pos] = (unsigned)code;
          }
        }
      }
    }
  }
}

// exact fp32 refine: per-row wave; each candidate lane replays the verified
// sequential ascending-c fused-FMA chain; d = fl(A - 2*G); min (d, k) lexicographic.
__global__ __launch_bounds__(256) void k_refine(const float* __restrict__ in,
                                                const float* __restrict__ cbk,
                                                const float* __restrict__ a2,
                                                const unsigned* __restrict__ cnt,
                                                const unsigned* __restrict__ cand,
                                                int* __restrict__ idx,
                                                float* __restrict__ idx_f) {
  __shared__ float xrow[4][256];
  const int w = threadIdx.x >> 6, lane = threadIdx.x & 63;
  const int n = (blockIdx.x << 2) + w;
  const int b = n >> 10, hw = n & 1023;
#pragma unroll
  for (int j = 0; j < 4; ++j) {
    const int c = (j << 6) + lane;
    xrow[w][c] = in[(((size_t)(b * DIM + c)) << 10) + hw];
  }
  __syncthreads();
  const unsigned cn = cnt[n];
  const int m = (int)(cn < CAND_CAP ? cn : CAND_CAP);
  unsigned long long key = ~0ull;
  if (lane < m) {
    const unsigned k = cand[(n << 4) + lane];
    const float* cp = cbk + ((size_t)k << 8);
    float acc = 0.f;
#pragma unroll 8
    for (int c = 0; c < 256; ++c) acc = __builtin_fmaf(xrow[w][c], cp[c], acc);
    const float d = __fadd_rn(a2[n], __fmul_rn(-2.0f, acc));
    key = ((unsigned long long)__float_as_uint(d) << 32) | (unsigned long long)k;
  }
#pragma unroll
  for (int off = 32; off >= 1; off >>= 1) {
    const unsigned long long o = __shfl_xor(key, off, 64);
    key = (o < key) ? o : key;
  }
  if (lane == 0) {
    const int bi = (int)(key & 0xFFFFFFFFull);
    idx[n] = bi;
    idx_f[n] = (float)bi;
  }
}

// insurance: rows with cnt > CAND_CAP get a full exact scan (expected ~0 rows)
__global__ __launch_bounds__(256) void k_fallback(const float* __restrict__ in,
                                                  const float* __restrict__ cbk,
                                                  const float* __restrict__ a2,
                                                  const unsigned* __restrict__ cnt,
                                                  int* __restrict__ idx,
                                                  float* __restrict__ idx_f) {
  __shared__ float xrow[256];
  __shared__ unsigned long long red[256];
  const int t = threadIdx.x;
  for (int n = blockIdx.x; n < NROWS; n += gridDim.x) {
    if (cnt[n] <= CAND_CAP) continue;
    const int b = n >> 10, hw = n & 1023;
    xrow[t] = in[(((size_t)(b * DIM + t)) << 10) + hw];
    __syncthreads();
    unsigned long long key = ~0ull;
    for (int k = t; k < NUM_CODES; k += 256) {
      const float* cp = cbk + ((size_t)k << 8);
      float acc = 0.f;
      for (int c = 0; c < 256; ++c) acc = __builtin_fmaf(xrow[c], cp[c], acc);
      const float d = __fadd_rn(a2[n], __fmul_rn(-2.0f, acc));
      const unsigned long long kk =
          ((unsigned long long)__float_as_uint(d) << 32) | (unsigned long long)k;
      key = (kk < key) ? kk : key;
    }
    red[t] = key;
    __syncthreads();
    for (int s = 128; s >= 1; s >>= 1) {
      if (t < s) red[t] = (red[t + s] < red[t]) ? red[t + s] : red[t];
      __syncthreads();
    }
    if (t == 0) {
      const int bi = (int)(red[0] & 0xFFFFFFFFull);
      idx[n] = bi;
      idx_f[n] = (float)bi;
    }
    __syncthreads();
  }
}

// =================== legacy path (R4-verified) ===================

__global__ __launch_bounds__(256, 2) void k_argmin_legacy(
    const float* __restrict__ in, const float* __restrict__ cbk,
    const float* __restrict__ a2, int* __restrict__ idx_out,
    float* __restrict__ idx_out_f) {
  __shared__ __align__(16) float xs[32 * 68];
  __shared__ __align__(16) float cs[32 * 260];
  const int tid = threadIdx.x;
  const int trow = tid >> 5;
  const int tcol = tid & 31;
  const int r0 = blockIdx.x << 6;
  const int bb = r0 >> 10;
  const int hw0 = r0 & 1023;
  float ar[8];
#pragma unroll
  for (int r = 0; r < 8; ++r) ar[r] = a2[r0 + (trow << 3) + r];
  float bd[8];
  int bi[8];
#pragma unroll
  for (int r = 0; r < 8; ++r) { bd[r] = 3.402823466e+38f; bi[r] = 0x7fffffff; }
  const int s_ck = tid >> 3;
  const int s_w4 = (tid & 7) << 2;
  for (int kb = 0; kb < NUM_CODES; kb += 256) {
    float acc[8][8];
#pragma unroll
    for (int r = 0; r < 8; ++r)
#pragma unroll
      for (int q = 0; q < 8; ++q) acc[r][q] = 0.f;
    for (int cb = 0; cb < DIM; cb += 32) {
      {
        const float* src = in + (((size_t)(bb * DIM + cb + s_ck)) << 10) + hw0 + s_w4;
        const float4 a = *(const float4*)(src);
        const float4 b = *(const float4*)(src + 32);
        *(float4*)&xs[s_ck * 68 + s_w4] = a;
        *(float4*)&xs[s_ck * 68 + s_w4 + 32] = b;
      }
#pragma unroll
      for (int i = 0; i < 8; ++i) {
        const int fid = tid + (i << 8);
        const int k = fid >> 3;
        const int c4 = (fid & 7) << 2;
        const float4 cv = *(const float4*)(cbk + (((size_t)(kb + k)) << 8) + cb + c4);
        cs[(c4 + 0) * 260 + k] = cv.x;
        cs[(c4 + 1) * 260 + k] = cv.y;
        cs[(c4 + 2) * 260 + k] = cv.z;
        cs[(c4 + 3) * 260 + k] = cv.w;
      }
      __syncthreads();
#pragma unroll 4
      for (int ck = 0; ck < 32; ++ck) {
        const float4 xa = *(const float4*)&xs[ck * 68 + (trow << 3)];
        const float4 xb = *(const float4*)&xs[ck * 68 + (trow << 3) + 4];
        const float4 ca = *(const float4*)&cs[ck * 260 + (tcol << 2)];
        const float4 cb2 = *(const float4*)&cs[ck * 260 + (tcol << 2) + 128];
        const float xv[8] = {xa.x, xa.y, xa.z, xa.w, xb.x, xb.y, xb.z, xb.w};
        const float cv[8] = {ca.x, ca.y, ca.z, ca.w, cb2.x, cb2.y, cb2.z, cb2.w};
#pragma unroll
        for (int r = 0; r < 8; ++r)
#pragma unroll
          for (int q = 0; q < 8; ++q) acc[r][q] = __builtin_fmaf(xv[r], cv[q], acc[r][q]);
      }
      __syncthreads();
    }
#pragma unroll
    for (int g = 0; g < 2; ++g)
#pragma unroll
      for (int j = 0; j < 4; ++j) {
        const int kk = kb + (tcol << 2) + j + (g << 7);
#pragma unroll
        for (int r = 0; r < 8; ++r) {
          const float d = __fadd_rn(ar[r], __fmul_rn(-2.0f, acc[r][(g << 2) + j]));
          if (d < bd[r]) { bd[r] = d; bi[r] = kk; }
        }
      }
  }
  __syncthreads();
  float2* red = (float2*)cs;
#pragma unroll
  for (int r = 0; r < 8; ++r)
    red[((trow << 3) + r) * 32 + tcol] = make_float2(bd[r], __int_as_float(bi[r]));
  __syncthreads();
  if (tid < 64) {
    float bestd = 3.402823466e+38f;
    int besti = 0x7fffffff;
    for (int c = 0; c < 32; ++c) {
      const float2 v = red[tid * 32 + c];
      const int vi = __float_as_int(v.y);
      if (v.x < bestd || (v.x == bestd && vi < besti)) { bestd = v.x; besti = vi; }
    }
    const int n = r0 + tid;
    idx_out[n] = besti;
    idx_out_f[n] = (float)besti;
  }
}

// =================== launch ===================

extern "C" void kernel_launch(void* const* d_in, const int* in_sizes, int n_in,
                              void* d_out, int out_size, void* d_ws, size_t ws_size,
                              hipStream_t stream) {
  const float* in = (const float*)d_in[0];
  const float* cbk = (const float*)d_in[1];
  float* out = (float*)d_out;
  char* ws = (char*)d_ws;

  if (ws_size >= (size_t)WF_END) {
    unsigned short* xt = (unsigned short*)(ws + WF_XT);
    unsigned short* cbb = (unsigned short*)(ws + WF_CB);
    float* a2 = (float*)(ws + WF_A2);
    unsigned* dmin = (unsigned*)(ws + WF_DMIN);
    unsigned* cnt = (unsigned*)(ws + WF_CNT);
    unsigned* cand = (unsigned*)(ws + WF_CAND);
    int* idx = (int*)(ws + WF_IDX);
    int* counts = (int*)(ws + WF_COUNTS);
    double* partials = (double*)(ws + WF_PART);

    hipMemsetAsync(dmin, 0xFF, NROWS * sizeof(unsigned), stream);
    hipMemsetAsync(cnt, 0, NROWS * sizeof(unsigned), stream);
    hipMemsetAsync(counts, 0, NUM_CODES * sizeof(int), stream);
    k_cvt_cb<<<NUM_CODES * DIM / (256 * 8), 256, 0, stream>>>(cbk, cbb);
    k_cvt_x<<<(NROWS / 64) * 4, 256, 0, stream>>>(in, xt);
    k_a2<<<NROWS / 256, 256, 0, stream>>>(in, a2);
    k_screen<1><<<(NROWS / 128) * (NUM_CODES / 128), 256, 0, stream>>>(xt, cbb, dmin, cnt, cand);
    k_screen<2><<<(NROWS / 128) * (NUM_CODES / 128), 256, 0, stream>>>(xt, cbb, dmin, cnt, cand);
    k_refine<<<NROWS / 4, 256, 0, stream>>>(in, cbk, a2, cnt, cand, idx, out + OUT_IDX);
    k_fallback<<<128, 256, 0, stream>>>(in, cbk, a2, cnt, idx, out + OUT_IDX);
    k_counts<<<NROWS / 256, 256, 0, stream>>>(idx, counts);
    k_quant<<<NELEM / 1024, 256, 0, stream>>>(in, cbk, idx, out + OUT_Q, partials);
    k_finalize<<<1, 256, 0, stream>>>(partials, counts, out + OUT_LOSS, out + OUT_PERP);
  } else {
    // legacy verified path
    float* a2 = (float*)(ws + WL_A2);
    int* idx = (int*)(ws + WL_IDX);
    int* counts = (int*)(ws + WL_COUNTS);
    double* partials = (double*)(ws + WL_PART);
    hipMemsetAsync(counts, 0, NUM_CODES * sizeof(int), stream);
    k_a2<<<NROWS / 256, 256, 0, stream>>>(in, a2);
    k_argmin_legacy<<<NROWS / 64, 256, 0, stream>>>(in, cbk, a2, idx, out + OUT_IDX);
    k_counts<<<NROWS / 256, 256, 0, stream>>>(idx, counts);
    k_quant<<<NELEM / 1024, 256, 0, stream>>>(in, cbk, idx, out + OUT_Q, partials);
    k_finalize<<<1, 256, 0, stream>>>(partials, counts, out + OUT_LOSS, out + OUT_PERP);
  }
}

// Round 6
// 1172.625 us; speedup vs baseline: 2.8558x; 2.8558x over previous
//
#include <hip/hip_runtime.h>
#include <math.h>

#define NUM_CODES 8192
#define DIM 256
#define NROWS 32768            // 32 * 32 * 32
#define NELEM (NROWS * DIM)    // 8388608

// d_out layout (fp32 elements): loss | quantized | perplexity | indices
#define OUT_LOSS 0
#define OUT_Q 1
#define OUT_PERP (1 + NELEM)
#define OUT_IDX (2 + NELEM)

#define DELTA 2e-4f
#define CAND_CAP 16
#define NQBLK (NELEM / 1024)

// ---- path A ws layout (bytes), needs 32 MB ----
#define WA_XT    0x0        // 32768*256 bf16 (16 MB)
#define WA_CB    0x1000000  // 8192*256 bf16 (4 MB)
#define WA_A2    0x1400000  // 32768 f32 (128 KB)
#define WA_BMIN  0x1420000  // 64*32768 f32 (8 MB)
#define WA_CNT   0x1C20000  // 32768 u32 (128 KB)
#define WA_CAND  0x1C40000  // 32768*16 u32 (2 MB)
#define WA_IDX   0x1E40000  // 32768 i32 (128 KB)
#define WA_COUNTS 0x1E60000 // 8192 i32 (32 KB)
#define WA_PART  0x1E68000  // 8192 f64 (64 KB)
#define WA_END   0x1E78000  // ~32 MB

// ---- path B ws layout (R5-proven footprint, 23.69 MB) ----
#define WF_XT    0x0
#define WF_CB    0x1000000
#define WF_A2    0x1400000
#define WF_DMIN  0x1420000
#define WF_CNT   0x1440000
#define WF_CAND  0x1460000
#define WF_IDX   0x1660000
#define WF_COUNTS 0x1680000
#define WF_PART  0x1688000
#define WF_END   0x1698000

// ---- legacy (R4-verified) ws layout ----
#define WL_A2 0
#define WL_IDX 0x20000
#define WL_COUNTS 0x40000
#define WL_PART 0x48000

typedef __bf16 bf16x8 __attribute__((ext_vector_type(8)));
typedef float f32x4 __attribute__((ext_vector_type(4)));

__device__ __forceinline__ unsigned f2bf_rne(float x) {
  const unsigned u = __float_as_uint(x);
  return (u + 0x7FFFu + ((u >> 16) & 1u)) >> 16;
}
__device__ __forceinline__ float bf2f(unsigned short h) {
  return __uint_as_float((unsigned)h << 16);
}

// =================== shared kernels ===================

// A[n] = np.sum(flat[n]**2), exact numpy pairwise fp32 (verified R3/R4)
__global__ __launch_bounds__(256) void k_a2(const float* __restrict__ in,
                                            float* __restrict__ a2) {
  const int n = (blockIdx.x << 8) + threadIdx.x;
  const int b = n >> 10, hw = n & 1023;
  const float* p = in + (((size_t)b) << 18) + hw;
  float s[2];
#pragma unroll
  for (int h = 0; h < 2; ++h) {
    const int c0 = h << 7;
    float r[8];
#pragma unroll
    for (int j = 0; j < 8; ++j) {
      const float v = p[(size_t)(c0 + j) << 10];
      r[j] = __fmul_rn(v, v);
    }
    for (int i = 8; i < 128; i += 8) {
#pragma unroll
      for (int j = 0; j < 8; ++j) {
        const float v = p[(size_t)(c0 + i + j) << 10];
        r[j] = __fadd_rn(r[j], __fmul_rn(v, v));
      }
    }
    s[h] = __fadd_rn(__fadd_rn(__fadd_rn(r[0], r[1]), __fadd_rn(r[2], r[3])),
                     __fadd_rn(__fadd_rn(r[4], r[5]), __fadd_rn(r[6], r[7])));
  }
  a2[n] = __fadd_rn(s[0], s[1]);
}

__global__ __launch_bounds__(256) void k_cvt_cb(const float* __restrict__ cbk,
                                                unsigned short* __restrict__ cbb) {
  const int e = (((blockIdx.x << 8) + threadIdx.x) << 3);
  const float4 a = *(const float4*)(cbk + e);
  const float4 b = *(const float4*)(cbk + e + 4);
  uint4 o;
  o.x = f2bf_rne(a.x) | (f2bf_rne(a.y) << 16);
  o.y = f2bf_rne(a.z) | (f2bf_rne(a.w) << 16);
  o.z = f2bf_rne(b.x) | (f2bf_rne(b.y) << 16);
  o.w = f2bf_rne(b.z) | (f2bf_rne(b.w) << 16);
  *(uint4*)(cbb + e) = o;
}

__global__ __launch_bounds__(256) void k_cvt_x(const float* __restrict__ in,
                                               unsigned short* __restrict__ xt) {
  __shared__ float t[64][65];
  const int tid = threadIdx.x;
  const int n0 = (blockIdx.x >> 2) << 6;
  const int c0 = (blockIdx.x & 3) << 6;
  const int b = n0 >> 10, hw0 = n0 & 1023;
#pragma unroll
  for (int i = 0; i < 4; ++i) {
    const int f = (i << 8) + tid;
    const int cl = f >> 4;
    const int h4 = (f & 15) << 2;
    const float4 v = *(const float4*)(in + (((size_t)(b * DIM + c0 + cl)) << 10) + hw0 + h4);
    t[cl][h4 + 0] = v.x;
    t[cl][h4 + 1] = v.y;
    t[cl][h4 + 2] = v.z;
    t[cl][h4 + 3] = v.w;
  }
  __syncthreads();
#pragma unroll
  for (int i = 0; i < 2; ++i) {
    const int f = (i << 8) + tid;
    const int nl = f >> 3;
    const int c8 = (f & 7) << 3;
    uint4 o;
    o.x = f2bf_rne(t[c8 + 0][nl]) | (f2bf_rne(t[c8 + 1][nl]) << 16);
    o.y = f2bf_rne(t[c8 + 2][nl]) | (f2bf_rne(t[c8 + 3][nl]) << 16);
    o.z = f2bf_rne(t[c8 + 4][nl]) | (f2bf_rne(t[c8 + 5][nl]) << 16);
    o.w = f2bf_rne(t[c8 + 6][nl]) | (f2bf_rne(t[c8 + 7][nl]) << 16);
    *(uint4*)&xt[(((size_t)(n0 + nl)) << 8) + c0 + c8] = o;
  }
}

__global__ __launch_bounds__(256) void k_quant(const float* __restrict__ in,
                                               const float* __restrict__ cbk,
                                               const int* __restrict__ idx,
                                               float* __restrict__ outq,
                                               double* __restrict__ partials) {
  const int tid = threadIdx.x;
  const int e = (blockIdx.x << 10) + (tid << 2);
  const int bc = e >> 10;
  const int hw = e & 1023;
  const int b = bc >> 8;
  const int c = bc & 255;
  const int nbase = (b << 10) + hw;
  const float4 x = *(const float4*)(in + e);
  const float xv[4] = {x.x, x.y, x.z, x.w};
  double ls = 0.0;
  float o[4];
#pragma unroll
  for (int j = 0; j < 4; ++j) {
    const int qi = idx[nbase + j];
    const float q = cbk[((size_t)qi << 8) + c];
    const float diff = q - xv[j];
    o[j] = xv[j] + diff;
    ls += (double)diff * (double)diff;
  }
  outq[e] = o[0];
  outq[e + 1] = o[1];
  outq[e + 2] = o[2];
  outq[e + 3] = o[3];
#pragma unroll
  for (int off = 32; off >= 1; off >>= 1) ls += __shfl_down(ls, off, 64);
  __shared__ double wsum[4];
  const int lane = tid & 63, wid = tid >> 6;
  if (lane == 0) wsum[wid] = ls;
  __syncthreads();
  if (tid == 0) partials[blockIdx.x] = wsum[0] + wsum[1] + wsum[2] + wsum[3];
}

__global__ __launch_bounds__(256) void k_counts(const int* __restrict__ idx,
                                                int* __restrict__ counts) {
  const int n = (blockIdx.x << 8) + threadIdx.x;
  atomicAdd(&counts[idx[n]], 1);
}

__global__ __launch_bounds__(256) void k_finalize(const double* __restrict__ partials,
                                                  const int* __restrict__ counts,
                                                  float* __restrict__ out_loss,
                                                  float* __restrict__ out_perp) {
  const int tid = threadIdx.x;
  double sl = 0.0, se = 0.0;
  for (int i = tid; i < NQBLK; i += 256) sl += partials[i];
  for (int k = tid; k < NUM_CODES; k += 256) {
    const double p = (double)counts[k] / 32768.0;
    se += p * log(p + 1e-10);
  }
#pragma unroll
  for (int off = 32; off >= 1; off >>= 1) {
    sl += __shfl_down(sl, off, 64);
    se += __shfl_down(se, off, 64);
  }
  __shared__ double sL[4], sE[4];
  const int lane = tid & 63, wid = tid >> 6;
  if (lane == 0) { sL[wid] = sl; sE[wid] = se; }
  __syncthreads();
  if (tid == 0) {
    const double L = sL[0] + sL[1] + sL[2] + sL[3];
    const double E = sE[0] + sE[1] + sE[2] + sE[3];
    const double m = L / (double)NELEM;
    *out_loss = (float)(m + 0.6 * m);
    *out_perp = (float)exp(-E);
  }
}

// =================== MFMA screen GEMMs ===================
// 128 rows x 128 codes per block, K=256 in 64-chunks. d~ = fl(1 - 2*G^).
#define XS_STR 72

// path A pass: writes per-(row, 128-code-block) min to bmin[nb][row]
__global__ __launch_bounds__(256, 4) void k_gemm_bmin(
    const unsigned short* __restrict__ xt, const unsigned short* __restrict__ cbb,
    float* __restrict__ bmin) {
  __shared__ __align__(16) unsigned short xs[128 * XS_STR];
  __shared__ __align__(16) unsigned short cs[128 * XS_STR];
  const int tid = threadIdx.x;
  const int lane = tid & 63;
  const int w = tid >> 6;
  const int wm = w >> 1, wn = w & 1;
  const int m0 = (blockIdx.x >> 6) << 7;
  const int nb = blockIdx.x & 63;
  const int n0 = nb << 7;
  const int quad = lane >> 4;
  const int l15 = lane & 15;

  f32x4 acc[4][4];
#pragma unroll
  for (int mt = 0; mt < 4; ++mt)
#pragma unroll
    for (int nt = 0; nt < 4; ++nt) acc[mt][nt] = (f32x4){0.f, 0.f, 0.f, 0.f};

  for (int ch0 = 0; ch0 < DIM; ch0 += 64) {
#pragma unroll
    for (int i = 0; i < 4; ++i) {
      const int f = (i << 8) + tid;
      const int row = f >> 3;
      const int k8 = (f & 7) << 3;
      *(uint4*)&xs[row * XS_STR + k8] = *(const uint4*)&xt[((m0 + row) << 8) + ch0 + k8];
      *(uint4*)&cs[row * XS_STR + k8] = *(const uint4*)&cbb[((n0 + row) << 8) + ch0 + k8];
    }
    __syncthreads();
#pragma unroll
    for (int ks = 0; ks < 2; ++ks) {
      bf16x8 af[4], bf_[4];
#pragma unroll
      for (int mt = 0; mt < 4; ++mt)
        af[mt] = *(const bf16x8*)&xs[((wm << 6) + (mt << 4) + l15) * XS_STR + (ks << 5) + (quad << 3)];
#pragma unroll
      for (int nt = 0; nt < 4; ++nt)
        bf_[nt] = *(const bf16x8*)&cs[((wn << 6) + (nt << 4) + l15) * XS_STR + (ks << 5) + (quad << 3)];
#pragma unroll
      for (int mt = 0; mt < 4; ++mt)
#pragma unroll
        for (int nt = 0; nt < 4; ++nt)
          acc[mt][nt] = __builtin_amdgcn_mfma_f32_16x16x32_bf16(af[mt], bf_[nt], acc[mt][nt], 0, 0, 0);
    }
    __syncthreads();
  }

  float* sred = (float*)cs;  // [2][128]
#pragma unroll
  for (int mt = 0; mt < 4; ++mt)
#pragma unroll
    for (int reg = 0; reg < 4; ++reg) {
      float v = 3.402823466e+38f;
#pragma unroll
      for (int nt = 0; nt < 4; ++nt) {
        const float d = __fadd_rn(1.0f, __fmul_rn(-2.0f, acc[mt][nt][reg]));
        v = fminf(v, d);
      }
      v = fminf(v, __shfl_xor(v, 1, 64));
      v = fminf(v, __shfl_xor(v, 2, 64));
      v = fminf(v, __shfl_xor(v, 4, 64));
      v = fminf(v, __shfl_xor(v, 8, 64));
      if (l15 == 0)
        sred[(wn << 7) + (wm << 6) + (mt << 4) + (quad << 2) + reg] = v;
    }
  __syncthreads();
  if (tid < 128)
    bmin[(size_t)nb * NROWS + m0 + tid] = fminf(sred[tid], sred[128 + tid]);
}

// path B pass (R5-verified): PASS 1 = global dmin; PASS 2 = collect window
template <int PASS>
__global__ __launch_bounds__(256, 4) void k_screen(
    const unsigned short* __restrict__ xt, const unsigned short* __restrict__ cbb,
    unsigned* __restrict__ dmin, unsigned* __restrict__ cnt,
    unsigned* __restrict__ cand) {
  __shared__ __align__(16) unsigned short xs[128 * XS_STR];
  __shared__ __align__(16) unsigned short cs[128 * XS_STR];
  const int tid = threadIdx.x;
  const int lane = tid & 63;
  const int w = tid >> 6;
  const int wm = w >> 1, wn = w & 1;
  const int m0 = (blockIdx.x >> 6) << 7;
  const int n0 = (blockIdx.x & 63) << 7;
  const int quad = lane >> 4;
  const int l15 = lane & 15;

  f32x4 acc[4][4];
#pragma unroll
  for (int mt = 0; mt < 4; ++mt)
#pragma unroll
    for (int nt = 0; nt < 4; ++nt) acc[mt][nt] = (f32x4){0.f, 0.f, 0.f, 0.f};

  for (int ch0 = 0; ch0 < DIM; ch0 += 64) {
#pragma unroll
    for (int i = 0; i < 4; ++i) {
      const int f = (i << 8) + tid;
      const int row = f >> 3;
      const int k8 = (f & 7) << 3;
      *(uint4*)&xs[row * XS_STR + k8] = *(const uint4*)&xt[((m0 + row) << 8) + ch0 + k8];
      *(uint4*)&cs[row * XS_STR + k8] = *(const uint4*)&cbb[((n0 + row) << 8) + ch0 + k8];
    }
    __syncthreads();
#pragma unroll
    for (int ks = 0; ks < 2; ++ks) {
      bf16x8 af[4], bf_[4];
#pragma unroll
      for (int mt = 0; mt < 4; ++mt)
        af[mt] = *(const bf16x8*)&xs[((wm << 6) + (mt << 4) + l15) * XS_STR + (ks << 5) + (quad << 3)];
#pragma unroll
      for (int nt = 0; nt < 4; ++nt)
        bf_[nt] = *(const bf16x8*)&cs[((wn << 6) + (nt << 4) + l15) * XS_STR + (ks << 5) + (quad << 3)];
#pragma unroll
      for (int mt = 0; mt < 4; ++mt)
#pragma unroll
        for (int nt = 0; nt < 4; ++nt)
          acc[mt][nt] = __builtin_amdgcn_mfma_f32_16x16x32_bf16(af[mt], bf_[nt], acc[mt][nt], 0, 0, 0);
    }
    __syncthreads();
  }

  if (PASS == 1) {
#pragma unroll
    for (int mt = 0; mt < 4; ++mt)
#pragma unroll
      for (int reg = 0; reg < 4; ++reg) {
        float v = 3.402823466e+38f;
#pragma unroll
        for (int nt = 0; nt < 4; ++nt) {
          const float d = __fadd_rn(1.0f, __fmul_rn(-2.0f, acc[mt][nt][reg]));
          v = fminf(v, d);
        }
        v = fminf(v, __shfl_xor(v, 1, 64));
        v = fminf(v, __shfl_xor(v, 2, 64));
        v = fminf(v, __shfl_xor(v, 4, 64));
        v = fminf(v, __shfl_xor(v, 8, 64));
        if (l15 == 0) {
          const int row = m0 + (wm << 6) + (mt << 4) + (quad << 2) + reg;
          atomicMin(&dmin[row], __float_as_uint(v));
        }
      }
  } else {
#pragma unroll
    for (int mt = 0; mt < 4; ++mt) {
      const int rowb = m0 + (wm << 6) + (mt << 4) + (quad << 2);
      float thr[4];
#pragma unroll
      for (int reg = 0; reg < 4; ++reg)
        thr[reg] = __uint_as_float(dmin[rowb + reg]) + DELTA;
#pragma unroll
      for (int nt = 0; nt < 4; ++nt) {
        const int code = n0 + (wn << 6) + (nt << 4) + l15;
#pragma unroll
        for (int reg = 0; reg < 4; ++reg) {
          const float d = __fadd_rn(1.0f, __fmul_rn(-2.0f, acc[mt][nt][reg]));
          if (d < thr[reg]) {
            const unsigned pos = atomicAdd(&cnt[rowb + reg], 1u);
            if (pos < CAND_CAP) cand[((rowb + reg) << 4) + pos] = (unsigned)code;
          }
        }
      }
    }
  }
}

// =================== path A candidate collection ===================
// 64 rows/block; per row: global min from 64 block-mins, recompute only
// qualifying 128-code blocks from bf16 data, emit candidate codes.
__global__ __launch_bounds__(256) void k_cand(const unsigned short* __restrict__ xt,
                                              const unsigned short* __restrict__ cbb,
                                              const float* __restrict__ bmin,
                                              unsigned* __restrict__ cnt,
                                              unsigned* __restrict__ cand) {
  __shared__ float bmt[64 * 65];     // [nb][row], pad-65 -> conflict-free column reads
  __shared__ float xrowf[4][256];
  const int tid = threadIdx.x, w = tid >> 6, lane = tid & 63;
  const int r0 = blockIdx.x << 6;
#pragma unroll
  for (int i = 0; i < 16; ++i) {
    const int nb = (i << 2) + w;
    bmt[nb * 65 + lane] = bmin[(size_t)nb * NROWS + r0 + lane];
  }
  __syncthreads();
  for (int j = 0; j < 16; ++j) {
    const int rloc = (w << 4) + j;
    const int n = r0 + rloc;
    {  // stage this row's bf16 x as f32 (wave-private slice)
      const ushort4 hv = *(const ushort4*)&xt[((size_t)n << 8) + (lane << 2)];
      float4 xv;
      xv.x = bf2f(hv.x); xv.y = bf2f(hv.y); xv.z = bf2f(hv.z); xv.w = bf2f(hv.w);
      *(float4*)&xrowf[w][lane << 2] = xv;
    }
    const float v = bmt[lane * 65 + rloc];
    float g = v;
    g = fminf(g, __shfl_xor(g, 32, 64));
    g = fminf(g, __shfl_xor(g, 16, 64));
    g = fminf(g, __shfl_xor(g, 8, 64));
    g = fminf(g, __shfl_xor(g, 4, 64));
    g = fminf(g, __shfl_xor(g, 2, 64));
    g = fminf(g, __shfl_xor(g, 1, 64));
    const float thr = g + DELTA;
    unsigned long long mask = __ballot(v <= thr);
    while (mask) {
      const int nb = (int)__builtin_ctzll(mask);
      mask &= mask - 1;
#pragma unroll
      for (int h = 0; h < 2; ++h) {
        const int k = (nb << 7) + (h << 6) + lane;
        const unsigned short* cp = cbb + ((size_t)k << 8);
        float a0 = 0.f, a1 = 0.f, a2v = 0.f, a3 = 0.f;
        for (int c = 0; c < 256; c += 8) {
          const ushort4 h0 = *(const ushort4*)(cp + c);
          const ushort4 h1 = *(const ushort4*)(cp + c + 4);
          a0 = __builtin_fmaf(xrowf[w][c + 0], bf2f(h0.x), a0);
          a1 = __builtin_fmaf(xrowf[w][c + 1], bf2f(h0.y), a1);
          a2v = __builtin_fmaf(xrowf[w][c + 2], bf2f(h0.z), a2v);
          a3 = __builtin_fmaf(xrowf[w][c + 3], bf2f(h0.w), a3);
          a0 = __builtin_fmaf(xrowf[w][c + 4], bf2f(h1.x), a0);
          a1 = __builtin_fmaf(xrowf[w][c + 5], bf2f(h1.y), a1);
          a2v = __builtin_fmaf(xrowf[w][c + 6], bf2f(h1.z), a2v);
          a3 = __builtin_fmaf(xrowf[w][c + 7], bf2f(h1.w), a3);
        }
        const float dot = (a0 + a1) + (a2v + a3);
        const float d = __fadd_rn(1.0f, __fmul_rn(-2.0f, dot));
        if (d < thr) {
          const unsigned pos = atomicAdd(&cnt[n], 1u);
          if (pos < CAND_CAP) cand[((size_t)n << 4) + pos] = (unsigned)k;
        }
      }
    }
  }
}

// =================== exact fp32 refine + insurance ===================
// 4 rows/block; coalesced float4 x staging; candidate lanes replay the
// verified sequential ascending-c fused-FMA chain; (d, k) lexicographic min.
__global__ __launch_bounds__(256) void k_refine(const float* __restrict__ in,
                                                const float* __restrict__ cbk,
                                                const float* __restrict__ a2,
                                                const unsigned* __restrict__ cnt,
                                                const unsigned* __restrict__ cand,
                                                int* __restrict__ idx,
                                                float* __restrict__ idx_f) {
  __shared__ float xrow[4][256];
  const int tid = threadIdx.x;
  const int n0 = blockIdx.x << 2;
  const int b = n0 >> 10, hw0 = n0 & 1023;
  {
    const float4 v = *(const float4*)(in + (((size_t)(b * DIM + tid)) << 10) + hw0);
    xrow[0][tid] = v.x; xrow[1][tid] = v.y; xrow[2][tid] = v.z; xrow[3][tid] = v.w;
  }
  __syncthreads();
  const int w = tid >> 6, lane = tid & 63;
  const int n = n0 + w;
  const unsigned cn = cnt[n];
  const int m = (int)(cn < (unsigned)CAND_CAP ? cn : (unsigned)CAND_CAP);
  unsigned long long key = ~0ull;
  if (lane < m) {
    const unsigned k = cand[((size_t)n << 4) + lane];
    const float* cp = cbk + ((size_t)k << 8);
    float acc = 0.f;
#pragma unroll
    for (int c = 0; c < 256; c += 4) {
      const float4 cv = *(const float4*)(cp + c);
      const float4 xv = *(const float4*)&xrow[w][c];
      acc = __builtin_fmaf(xv.x, cv.x, acc);
      acc = __builtin_fmaf(xv.y, cv.y, acc);
      acc = __builtin_fmaf(xv.z, cv.z, acc);
      acc = __builtin_fmaf(xv.w, cv.w, acc);
    }
    const float d = __fadd_rn(a2[n], __fmul_rn(-2.0f, acc));
    key = ((unsigned long long)__float_as_uint(d) << 32) | (unsigned long long)k;
  }
#pragma unroll
  for (int off = 8; off >= 1; off >>= 1) {
    const unsigned long long o = __shfl_xor(key, off, 64);
    key = (o < key) ? o : key;
  }
  if (lane == 0) {
    const int bi = (int)(key & 0xFFFFFFFFull);
    idx[n] = bi;
    idx_f[n] = (float)bi;
  }
}

// rows with cnt > CAND_CAP: full exact scan (rare); 512 blocks, float4 chains
__global__ __launch_bounds__(256) void k_fallback(const float* __restrict__ in,
                                                  const float* __restrict__ cbk,
                                                  const float* __restrict__ a2,
                                                  const unsigned* __restrict__ cnt,
                                                  int* __restrict__ idx,
                                                  float* __restrict__ idx_f) {
  __shared__ float xrow[256];
  __shared__ unsigned long long red[256];
  const int t = threadIdx.x;
  for (int n = blockIdx.x; n < NROWS; n += 512) {
    if (cnt[n] <= (unsigned)CAND_CAP) continue;
    const int b = n >> 10, hw = n & 1023;
    xrow[t] = in[(((size_t)(b * DIM + t)) << 10) + hw];
    __syncthreads();
    unsigned long long key = ~0ull;
    for (int k = t; k < NUM_CODES; k += 256) {
      const float* cp = cbk + ((size_t)k << 8);
      float acc = 0.f;
#pragma unroll
      for (int c = 0; c < 256; c += 4) {
        const float4 cv = *(const float4*)(cp + c);
        acc = __builtin_fmaf(xrow[c + 0], cv.x, acc);
        acc = __builtin_fmaf(xrow[c + 1], cv.y, acc);
        acc = __builtin_fmaf(xrow[c + 2], cv.z, acc);
        acc = __builtin_fmaf(xrow[c + 3], cv.w, acc);
      }
      const float d = __fadd_rn(a2[n], __fmul_rn(-2.0f, acc));
      const unsigned long long kk =
          ((unsigned long long)__float_as_uint(d) << 32) | (unsigned long long)k;
      key = (kk < key) ? kk : key;
    }
    red[t] = key;
    __syncthreads();
    for (int s = 128; s >= 1; s >>= 1) {
      if (t < s) red[t] = (red[t + s] < red[t]) ? red[t + s] : red[t];
      __syncthreads();
    }
    if (t == 0) {
      const int bi = (int)(red[0] & 0xFFFFFFFFull);
      idx[n] = bi;
      idx_f[n] = (float)bi;
    }
    __syncthreads();
  }
}

// =================== legacy path (R4-verified) ===================
__global__ __launch_bounds__(256, 2) void k_argmin_legacy(
    const float* __restrict__ in, const float* __restrict__ cbk,
    const float* __restrict__ a2, int* __restrict__ idx_out,
    float* __restrict__ idx_out_f) {
  __shared__ __align__(16) float xs[32 * 68];
  __shared__ __align__(16) float cs[32 * 260];
  const int tid = threadIdx.x;
  const int trow = tid >> 5;
  const int tcol = tid & 31;
  const int r0 = blockIdx.x << 6;
  const int bb = r0 >> 10;
  const int hw0 = r0 & 1023;
  float ar[8];
#pragma unroll
  for (int r = 0; r < 8; ++r) ar[r] = a2[r0 + (trow << 3) + r];
  float bd[8];
  int bi[8];
#pragma unroll
  for (int r = 0; r < 8; ++r) { bd[r] = 3.402823466e+38f; bi[r] = 0x7fffffff; }
  const int s_ck = tid >> 3;
  const int s_w4 = (tid & 7) << 2;
  for (int kb = 0; kb < NUM_CODES; kb += 256) {
    float acc[8][8];
#pragma unroll
    for (int r = 0; r < 8; ++r)
#pragma unroll
      for (int q = 0; q < 8; ++q) acc[r][q] = 0.f;
    for (int cb = 0; cb < DIM; cb += 32) {
      {
        const float* src = in + (((size_t)(bb * DIM + cb + s_ck)) << 10) + hw0 + s_w4;
        const float4 a = *(const float4*)(src);
        const float4 b = *(const float4*)(src + 32);
        *(float4*)&xs[s_ck * 68 + s_w4] = a;
        *(float4*)&xs[s_ck * 68 + s_w4 + 32] = b;
      }
#pragma unroll
      for (int i = 0; i < 8; ++i) {
        const int fid = tid + (i << 8);
        const int k = fid >> 3;
        const int c4 = (fid & 7) << 2;
        const float4 cv = *(const float4*)(cbk + (((size_t)(kb + k)) << 8) + cb + c4);
        cs[(c4 + 0) * 260 + k] = cv.x;
        cs[(c4 + 1) * 260 + k] = cv.y;
        cs[(c4 + 2) * 260 + k] = cv.z;
        cs[(c4 + 3) * 260 + k] = cv.w;
      }
      __syncthreads();
#pragma unroll 4
      for (int ck = 0; ck < 32; ++ck) {
        const float4 xa = *(const float4*)&xs[ck * 68 + (trow << 3)];
        const float4 xb = *(const float4*)&xs[ck * 68 + (trow << 3) + 4];
        const float4 ca = *(const float4*)&cs[ck * 260 + (tcol << 2)];
        const float4 cb2 = *(const float4*)&cs[ck * 260 + (tcol << 2) + 128];
        const float xv[8] = {xa.x, xa.y, xa.z, xa.w, xb.x, xb.y, xb.z, xb.w};
        const float cv[8] = {ca.x, ca.y, ca.z, ca.w, cb2.x, cb2.y, cb2.z, cb2.w};
#pragma unroll
        for (int r = 0; r < 8; ++r)
#pragma unroll
          for (int q = 0; q < 8; ++q) acc[r][q] = __builtin_fmaf(xv[r], cv[q], acc[r][q]);
      }
      __syncthreads();
    }
#pragma unroll
    for (int g = 0; g < 2; ++g)
#pragma unroll
      for (int j = 0; j < 4; ++j) {
        const int kk = kb + (tcol << 2) + j + (g << 7);
#pragma unroll
        for (int r = 0; r < 8; ++r) {
          const float d = __fadd_rn(ar[r], __fmul_rn(-2.0f, acc[r][(g << 2) + j]));
          if (d < bd[r]) { bd[r] = d; bi[r] = kk; }
        }
      }
  }
  __syncthreads();
  float2* red = (float2*)cs;
#pragma unroll
  for (int r = 0; r < 8; ++r)
    red[((trow << 3) + r) * 32 + tcol] = make_float2(bd[r], __int_as_float(bi[r]));
  __syncthreads();
  if (tid < 64) {
    float bestd = 3.402823466e+38f;
    int besti = 0x7fffffff;
    for (int c = 0; c < 32; ++c) {
      const float2 v = red[tid * 32 + c];
      const int vi = __float_as_int(v.y);
      if (v.x < bestd || (v.x == bestd && vi < besti)) { bestd = v.x; besti = vi; }
    }
    const int n = r0 + tid;
    idx_out[n] = besti;
    idx_out_f[n] = (float)besti;
  }
}

// =================== launch ===================
extern "C" void kernel_launch(void* const* d_in, const int* in_sizes, int n_in,
                              void* d_out, int out_size, void* d_ws, size_t ws_size,
                              hipStream_t stream) {
  const float* in = (const float*)d_in[0];
  const float* cbk = (const float*)d_in[1];
  float* out = (float*)d_out;
  char* ws = (char*)d_ws;

  if (ws_size >= (size_t)WA_END) {
    // ---- path A: one GEMM + block-min candidate collection ----
    unsigned short* xt = (unsigned short*)(ws + WA_XT);
    unsigned short* cbb = (unsigned short*)(ws + WA_CB);
    float* a2 = (float*)(ws + WA_A2);
    float* bmin = (float*)(ws + WA_BMIN);
    unsigned* cnt = (unsigned*)(ws + WA_CNT);
    unsigned* cand = (unsigned*)(ws + WA_CAND);
    int* idx = (int*)(ws + WA_IDX);
    int* counts = (int*)(ws + WA_COUNTS);
    double* partials = (double*)(ws + WA_PART);

    hipMemsetAsync(cnt, 0, NROWS * sizeof(unsigned), stream);
    hipMemsetAsync(counts, 0, NUM_CODES * sizeof(int), stream);
    k_cvt_cb<<<NUM_CODES * DIM / (256 * 8), 256, 0, stream>>>(cbk, cbb);
    k_cvt_x<<<(NROWS / 64) * 4, 256, 0, stream>>>(in, xt);
    k_a2<<<NROWS / 256, 256, 0, stream>>>(in, a2);
    k_gemm_bmin<<<(NROWS / 128) * (NUM_CODES / 128), 256, 0, stream>>>(xt, cbb, bmin);
    k_cand<<<NROWS / 64, 256, 0, stream>>>(xt, cbb, bmin, cnt, cand);
    k_refine<<<NROWS / 4, 256, 0, stream>>>(in, cbk, a2, cnt, cand, idx, out + OUT_IDX);
    k_fallback<<<512, 256, 0, stream>>>(in, cbk, a2, cnt, idx, out + OUT_IDX);
    k_counts<<<NROWS / 256, 256, 0, stream>>>(idx, counts);
    k_quant<<<NELEM / 1024, 256, 0, stream>>>(in, cbk, idx, out + OUT_Q, partials);
    k_finalize<<<1, 256, 0, stream>>>(partials, counts, out + OUT_LOSS, out + OUT_PERP);
  } else if (ws_size >= (size_t)WF_END) {
    // ---- path B: two-GEMM screen (R5 footprint) + fixed tail ----
    unsigned short* xt = (unsigned short*)(ws + WF_XT);
    unsigned short* cbb = (unsigned short*)(ws + WF_CB);
    float* a2 = (float*)(ws + WF_A2);
    unsigned* dmin = (unsigned*)(ws + WF_DMIN);
    unsigned* cnt = (unsigned*)(ws + WF_CNT);
    unsigned* cand = (unsigned*)(ws + WF_CAND);
    int* idx = (int*)(ws + WF_IDX);
    int* counts = (int*)(ws + WF_COUNTS);
    double* partials = (double*)(ws + WF_PART);

    hipMemsetAsync(dmin, 0xFF, NROWS * sizeof(unsigned), stream);
    hipMemsetAsync(cnt, 0, NROWS * sizeof(unsigned), stream);
    hipMemsetAsync(counts, 0, NUM_CODES * sizeof(int), stream);
    k_cvt_cb<<<NUM_CODES * DIM / (256 * 8), 256, 0, stream>>>(cbk, cbb);
    k_cvt_x<<<(NROWS / 64) * 4, 256, 0, stream>>>(in, xt);
    k_a2<<<NROWS / 256, 256, 0, stream>>>(in, a2);
    k_screen<1><<<(NROWS / 128) * (NUM_CODES / 128), 256, 0, stream>>>(xt, cbb, dmin, cnt, cand);
    k_screen<2><<<(NROWS / 128) * (NUM_CODES / 128), 256, 0, stream>>>(xt, cbb, dmin, cnt, cand);
    k_refine<<<NROWS / 4, 256, 0, stream>>>(in, cbk, a2, cnt, cand, idx, out + OUT_IDX);
    k_fallback<<<512, 256, 0, stream>>>(in, cbk, a2, cnt, idx, out + OUT_IDX);
    k_counts<<<NROWS / 256, 256, 0, stream>>>(idx, counts);
    k_quant<<<NELEM / 1024, 256, 0, stream>>>(in, cbk, idx, out + OUT_Q, partials);
    k_finalize<<<1, 256, 0, stream>>>(partials, counts, out + OUT_LOSS, out + OUT_PERP);
  } else {
    // ---- legacy verified path ----
    float* a2 = (float*)(ws + WL_A2);
    int* idx = (int*)(ws + WL_IDX);
    int* counts = (int*)(ws + WL_COUNTS);
    double* partials = (double*)(ws + WL_PART);
    hipMemsetAsync(counts, 0, NUM_CODES * sizeof(int), stream);
    k_a2<<<NROWS / 256, 256, 0, stream>>>(in, a2);
    k_argmin_legacy<<<NROWS / 64, 256, 0, stream>>>(in, cbk, a2, idx, out + OUT_IDX);
    k_counts<<<NROWS / 256, 256, 0, stream>>>(idx, counts);
    k_quant<<<NELEM / 1024, 256, 0, stream>>>(in, cbk, idx, out + OUT_Q, partials);
    k_finalize<<<1, 256, 0, stream>>>(partials, counts, out + OUT_LOSS, out + OUT_PERP);
  }
}

// Round 7
// 967.251 us; speedup vs baseline: 3.4621x; 1.2123x over previous
//
#include <hip/hip_runtime.h>
#include <math.h>

#define NUM_CODES 8192
#define DIM 256
#define NROWS 32768            // 32 * 32 * 32
#define NELEM (NROWS * DIM)    // 8388608

// d_out layout (fp32 elements): loss | quantized | perplexity | indices
#define OUT_LOSS 0
#define OUT_Q 1
#define OUT_PERP (1 + NELEM)
#define OUT_IDX (2 + NELEM)

#define DELTA 2e-4f
#define CAND_CAP 8
#define QCAP 262144
#define DOTS_BLOCKS 2048
#define NQBLK (NELEM / 1024)

// ---- ws layout (bytes); END fits under the PROVEN 31.97 MB bound ----
#define WX_XT    0x0        // 32768*256 bf16 (16 MB)
#define WX_CBB   0x1000000  // 8192*256 bf16 (4 MB)
#define WX_A2    0x1400000  // 32768 f32 (128 KB)
#define WX_BMIN  0x1420000  // 64*32768 f32 (8 MB) -- dead after k_queue; aliased:
#define WX_CBT   (WX_BMIN)              // 8192*256 bf16 transposed (4 MB)
#define WX_IDX   (WX_BMIN + 0x400000)   // 32768 i32
#define WX_COUNTS (WX_BMIN + 0x420000)  // 8192 i32
#define WX_PART  (WX_BMIN + 0x428000)   // 8192 f64
#define WX_THR   0x1C20000  // 32768 f32 (128 KB)
#define WX_CNT   0x1C40000  // 32768 u32 (128 KB)
#define WX_CAND  0x1C60000  // 32768*8 u32 (1 MB)
#define WX_QCNT  0x1D60000  // 4 KB
#define WX_QUEUE 0x1D61000  // 262144 u32 (1 MB)
#define WX_END   0x1E61000  // 31.85 MB < proven 31.97 MB

// ---- legacy (R4-verified) ws layout ----
#define WL_A2 0
#define WL_IDX 0x20000
#define WL_COUNTS 0x40000
#define WL_PART 0x48000

typedef __bf16 bf16x8 __attribute__((ext_vector_type(8)));
typedef float f32x4 __attribute__((ext_vector_type(4)));

__device__ __forceinline__ unsigned f2bf_rne(float x) {
  const unsigned u = __float_as_uint(x);
  return (u + 0x7FFFu + ((u >> 16) & 1u)) >> 16;
}
__device__ __forceinline__ float bf2f(unsigned short h) {
  return __uint_as_float((unsigned)h << 16);
}

// =================== shared kernels ===================

// A[n] = np.sum(flat[n]**2), exact numpy pairwise fp32 (verified R3-R6)
__global__ __launch_bounds__(256) void k_a2(const float* __restrict__ in,
                                            float* __restrict__ a2) {
  const int n = (blockIdx.x << 8) + threadIdx.x;
  const int b = n >> 10, hw = n & 1023;
  const float* p = in + (((size_t)b) << 18) + hw;
  float s[2];
#pragma unroll
  for (int h = 0; h < 2; ++h) {
    const int c0 = h << 7;
    float r[8];
#pragma unroll
    for (int j = 0; j < 8; ++j) {
      const float v = p[(size_t)(c0 + j) << 10];
      r[j] = __fmul_rn(v, v);
    }
    for (int i = 8; i < 128; i += 8) {
#pragma unroll
      for (int j = 0; j < 8; ++j) {
        const float v = p[(size_t)(c0 + i + j) << 10];
        r[j] = __fadd_rn(r[j], __fmul_rn(v, v));
      }
    }
    s[h] = __fadd_rn(__fadd_rn(__fadd_rn(r[0], r[1]), __fadd_rn(r[2], r[3])),
                     __fadd_rn(__fadd_rn(r[4], r[5]), __fadd_rn(r[6], r[7])));
  }
  a2[n] = __fadd_rn(s[0], s[1]);
}

__global__ __launch_bounds__(256) void k_cvt_cb(const float* __restrict__ cbk,
                                                unsigned short* __restrict__ cbb) {
  const int e = (((blockIdx.x << 8) + threadIdx.x) << 3);
  const float4 a = *(const float4*)(cbk + e);
  const float4 b = *(const float4*)(cbk + e + 4);
  uint4 o;
  o.x = f2bf_rne(a.x) | (f2bf_rne(a.y) << 16);
  o.y = f2bf_rne(a.z) | (f2bf_rne(a.w) << 16);
  o.z = f2bf_rne(b.x) | (f2bf_rne(b.y) << 16);
  o.w = f2bf_rne(b.z) | (f2bf_rne(b.w) << 16);
  *(uint4*)(cbb + e) = o;
}

__global__ __launch_bounds__(256) void k_cvt_x(const float* __restrict__ in,
                                               unsigned short* __restrict__ xt) {
  __shared__ float t[64][65];
  const int tid = threadIdx.x;
  const int n0 = (blockIdx.x >> 2) << 6;
  const int c0 = (blockIdx.x & 3) << 6;
  const int b = n0 >> 10, hw0 = n0 & 1023;
#pragma unroll
  for (int i = 0; i < 4; ++i) {
    const int f = (i << 8) + tid;
    const int cl = f >> 4;
    const int h4 = (f & 15) << 2;
    const float4 v = *(const float4*)(in + (((size_t)(b * DIM + c0 + cl)) << 10) + hw0 + h4);
    t[cl][h4 + 0] = v.x;
    t[cl][h4 + 1] = v.y;
    t[cl][h4 + 2] = v.z;
    t[cl][h4 + 3] = v.w;
  }
  __syncthreads();
#pragma unroll
  for (int i = 0; i < 2; ++i) {
    const int f = (i << 8) + tid;
    const int nl = f >> 3;
    const int c8 = (f & 7) << 3;
    uint4 o;
    o.x = f2bf_rne(t[c8 + 0][nl]) | (f2bf_rne(t[c8 + 1][nl]) << 16);
    o.y = f2bf_rne(t[c8 + 2][nl]) | (f2bf_rne(t[c8 + 3][nl]) << 16);
    o.z = f2bf_rne(t[c8 + 4][nl]) | (f2bf_rne(t[c8 + 5][nl]) << 16);
    o.w = f2bf_rne(t[c8 + 6][nl]) | (f2bf_rne(t[c8 + 7][nl]) << 16);
    *(uint4*)&xt[(((size_t)(n0 + nl)) << 8) + c0 + c8] = o;
  }
}

// codebook fp32 [k][c] -> TRANSPOSED bf16 cbt[c][k] (same RNE values as cbb)
__global__ __launch_bounds__(256) void k_cvt_t(const float* __restrict__ cbk,
                                               unsigned short* __restrict__ cbt) {
  __shared__ unsigned short tl[64][68];
  const int tid = threadIdx.x;
  const int kb = (blockIdx.x >> 2) << 6;
  const int cb = (blockIdx.x & 3) << 6;
#pragma unroll
  for (int i = 0; i < 4; ++i) {
    const int f = (i << 8) + tid;
    const int kl = f >> 4;
    const int c4 = (f & 15) << 2;
    const float4 v = *(const float4*)(cbk + ((size_t)(kb + kl) << 8) + cb + c4);
    tl[kl][c4 + 0] = (unsigned short)f2bf_rne(v.x);
    tl[kl][c4 + 1] = (unsigned short)f2bf_rne(v.y);
    tl[kl][c4 + 2] = (unsigned short)f2bf_rne(v.z);
    tl[kl][c4 + 3] = (unsigned short)f2bf_rne(v.w);
  }
  __syncthreads();
#pragma unroll
  for (int i = 0; i < 4; ++i) {
    const int f = (i << 8) + tid;
    const int cl = f >> 4;
    const int k4 = (f & 15) << 2;
    ushort4 o;
    o.x = tl[k4 + 0][cl];
    o.y = tl[k4 + 1][cl];
    o.z = tl[k4 + 2][cl];
    o.w = tl[k4 + 3][cl];
    *(ushort4*)&cbt[((size_t)(cb + cl) << 13) + kb + k4] = o;
  }
}

__global__ __launch_bounds__(256) void k_quant(const float* __restrict__ in,
                                               const float* __restrict__ cbk,
                                               const int* __restrict__ idx,
                                               float* __restrict__ outq,
                                               double* __restrict__ partials) {
  const int tid = threadIdx.x;
  const int e = (blockIdx.x << 10) + (tid << 2);
  const int bc = e >> 10;
  const int hw = e & 1023;
  const int b = bc >> 8;
  const int c = bc & 255;
  const int nbase = (b << 10) + hw;
  const float4 x = *(const float4*)(in + e);
  const float xv[4] = {x.x, x.y, x.z, x.w};
  double ls = 0.0;
  float o[4];
#pragma unroll
  for (int j = 0; j < 4; ++j) {
    const int qi = idx[nbase + j];
    const float q = cbk[((size_t)qi << 8) + c];
    const float diff = q - xv[j];
    o[j] = xv[j] + diff;
    ls += (double)diff * (double)diff;
  }
  outq[e] = o[0];
  outq[e + 1] = o[1];
  outq[e + 2] = o[2];
  outq[e + 3] = o[3];
#pragma unroll
  for (int off = 32; off >= 1; off >>= 1) ls += __shfl_down(ls, off, 64);
  __shared__ double wsum[4];
  const int lane = tid & 63, wid = tid >> 6;
  if (lane == 0) wsum[wid] = ls;
  __syncthreads();
  if (tid == 0) partials[blockIdx.x] = wsum[0] + wsum[1] + wsum[2] + wsum[3];
}

__global__ __launch_bounds__(256) void k_counts(const int* __restrict__ idx,
                                                int* __restrict__ counts) {
  const int n = (blockIdx.x << 8) + threadIdx.x;
  atomicAdd(&counts[idx[n]], 1);
}

__global__ __launch_bounds__(256) void k_finalize(const double* __restrict__ partials,
                                                  const int* __restrict__ counts,
                                                  float* __restrict__ out_loss,
                                                  float* __restrict__ out_perp) {
  const int tid = threadIdx.x;
  double sl = 0.0, se = 0.0;
  for (int i = tid; i < NQBLK; i += 256) sl += partials[i];
  for (int k = tid; k < NUM_CODES; k += 256) {
    const double p = (double)counts[k] / 32768.0;
    se += p * log(p + 1e-10);
  }
#pragma unroll
  for (int off = 32; off >= 1; off >>= 1) {
    sl += __shfl_down(sl, off, 64);
    se += __shfl_down(se, off, 64);
  }
  __shared__ double sL[4], sE[4];
  const int lane = tid & 63, wid = tid >> 6;
  if (lane == 0) { sL[wid] = sl; sE[wid] = se; }
  __syncthreads();
  if (tid == 0) {
    const double L = sL[0] + sL[1] + sL[2] + sL[3];
    const double E = sE[0] + sE[1] + sE[2] + sE[3];
    const double m = L / (double)NELEM;
    *out_loss = (float)(m + 0.6 * m);
    *out_perp = (float)exp(-E);
  }
}

// =================== MFMA screen GEMM (R6-verified) ===================
// 128 rows x 128 codes per block, K=256 in 64-chunks. d~ = fl(1 - 2*G^).
// Writes per-(row, 128-code-block) min to bmin[nb][row].
#define XS_STR 72
__global__ __launch_bounds__(256, 4) void k_gemm_bmin(
    const unsigned short* __restrict__ xt, const unsigned short* __restrict__ cbb,
    float* __restrict__ bmin) {
  __shared__ __align__(16) unsigned short xs[128 * XS_STR];
  __shared__ __align__(16) unsigned short cs[128 * XS_STR];
  const int tid = threadIdx.x;
  const int lane = tid & 63;
  const int w = tid >> 6;
  const int wm = w >> 1, wn = w & 1;
  const int m0 = (blockIdx.x >> 6) << 7;
  const int nb = blockIdx.x & 63;
  const int n0 = nb << 7;
  const int quad = lane >> 4;
  const int l15 = lane & 15;

  f32x4 acc[4][4];
#pragma unroll
  for (int mt = 0; mt < 4; ++mt)
#pragma unroll
    for (int nt = 0; nt < 4; ++nt) acc[mt][nt] = (f32x4){0.f, 0.f, 0.f, 0.f};

  for (int ch0 = 0; ch0 < DIM; ch0 += 64) {
#pragma unroll
    for (int i = 0; i < 4; ++i) {
      const int f = (i << 8) + tid;
      const int row = f >> 3;
      const int k8 = (f & 7) << 3;
      *(uint4*)&xs[row * XS_STR + k8] = *(const uint4*)&xt[((m0 + row) << 8) + ch0 + k8];
      *(uint4*)&cs[row * XS_STR + k8] = *(const uint4*)&cbb[((n0 + row) << 8) + ch0 + k8];
    }
    __syncthreads();
#pragma unroll
    for (int ks = 0; ks < 2; ++ks) {
      bf16x8 af[4], bf_[4];
#pragma unroll
      for (int mt = 0; mt < 4; ++mt)
        af[mt] = *(const bf16x8*)&xs[((wm << 6) + (mt << 4) + l15) * XS_STR + (ks << 5) + (quad << 3)];
#pragma unroll
      for (int nt = 0; nt < 4; ++nt)
        bf_[nt] = *(const bf16x8*)&cs[((wn << 6) + (nt << 4) + l15) * XS_STR + (ks << 5) + (quad << 3)];
#pragma unroll
      for (int mt = 0; mt < 4; ++mt)
#pragma unroll
        for (int nt = 0; nt < 4; ++nt)
          acc[mt][nt] = __builtin_amdgcn_mfma_f32_16x16x32_bf16(af[mt], bf_[nt], acc[mt][nt], 0, 0, 0);
    }
    __syncthreads();
  }

  float* sred = (float*)cs;  // [2][128]
#pragma unroll
  for (int mt = 0; mt < 4; ++mt)
#pragma unroll
    for (int reg = 0; reg < 4; ++reg) {
      float v = 3.402823466e+38f;
#pragma unroll
      for (int nt = 0; nt < 4; ++nt) {
        const float d = __fadd_rn(1.0f, __fmul_rn(-2.0f, acc[mt][nt][reg]));
        v = fminf(v, d);
      }
      v = fminf(v, __shfl_xor(v, 1, 64));
      v = fminf(v, __shfl_xor(v, 2, 64));
      v = fminf(v, __shfl_xor(v, 4, 64));
      v = fminf(v, __shfl_xor(v, 8, 64));
      if (l15 == 0)
        sred[(wn << 7) + (wm << 6) + (mt << 4) + (quad << 2) + reg] = v;
    }
  __syncthreads();
  if (tid < 128)
    bmin[(size_t)nb * NROWS + m0 + tid] = fminf(sred[tid], sred[128 + tid]);
}

// =================== candidate pipeline ===================

// per 64-row block: per-row global min + thr; push qualifying (row, nb) pairs
__global__ __launch_bounds__(256) void k_queue(const float* __restrict__ bmin,
                                               float* __restrict__ thrbuf,
                                               unsigned* __restrict__ qcnt,
                                               unsigned* __restrict__ queue,
                                               unsigned* __restrict__ cnt) {
  __shared__ float bmt[64 * 65];
  const int tid = threadIdx.x, w = tid >> 6, lane = tid & 63;
  const int r0 = blockIdx.x << 6;
#pragma unroll
  for (int i = 0; i < 16; ++i) {
    const int nb = (i << 2) + w;
    bmt[nb * 65 + lane] = bmin[(size_t)nb * NROWS + r0 + lane];
  }
  __syncthreads();
  for (int j = 0; j < 16; ++j) {
    const int rloc = (w << 4) + j;
    const int n = r0 + rloc;
    const float v = bmt[lane * 65 + rloc];
    float g = v;
    g = fminf(g, __shfl_xor(g, 32, 64));
    g = fminf(g, __shfl_xor(g, 16, 64));
    g = fminf(g, __shfl_xor(g, 8, 64));
    g = fminf(g, __shfl_xor(g, 4, 64));
    g = fminf(g, __shfl_xor(g, 2, 64));
    g = fminf(g, __shfl_xor(g, 1, 64));
    const float thr = g + DELTA;
    if (lane == 0) thrbuf[n] = thr;
    if (v <= thr) {
      const unsigned pos = atomicAdd(qcnt, 1u);
      if (pos < (unsigned)QCAP) queue[pos] = ((unsigned)n << 6) | (unsigned)lane;
      else atomicAdd(&cnt[n], 64u);  // force exact fallback for this row
    }
  }
}

// one wave per queued (row, nb) pair: 2 codes/lane, coalesced cbt loads
__global__ __launch_bounds__(256) void k_dots(const unsigned short* __restrict__ xt,
                                              const unsigned short* __restrict__ cbt,
                                              const float* __restrict__ thrbuf,
                                              const unsigned* __restrict__ qcnt,
                                              const unsigned* __restrict__ queue,
                                              unsigned* __restrict__ cnt,
                                              unsigned* __restrict__ cand) {
  __shared__ float xr[4][256];
  const int tid = threadIdx.x, w = tid >> 6, lane = tid & 63;
  const unsigned qv = *qcnt;
  const int qn = (int)(qv < (unsigned)QCAP ? qv : (unsigned)QCAP);
  const unsigned* c32 = (const unsigned*)cbt;  // [c][k/2] u32 pairs
  for (int p = (blockIdx.x << 2) + w; p < qn; p += (DOTS_BLOCKS << 2)) {
    const unsigned pr = queue[p];
    const int n = (int)(pr >> 6), nb = (int)(pr & 63u);
    {
      const ushort4 hv = *(const ushort4*)&xt[((size_t)n << 8) + (lane << 2)];
      xr[w][(lane << 2) + 0] = bf2f(hv.x);
      xr[w][(lane << 2) + 1] = bf2f(hv.y);
      xr[w][(lane << 2) + 2] = bf2f(hv.z);
      xr[w][(lane << 2) + 3] = bf2f(hv.w);
    }
    asm volatile("s_waitcnt lgkmcnt(0)" ::: "memory");  // wave-local LDS visibility
    const float thr = thrbuf[n];
    const unsigned* cp = c32 + (nb << 6) + lane;
    float a0 = 0.f, a1 = 0.f;
#pragma unroll 8
    for (int c = 0; c < 256; ++c) {
      const unsigned u = cp[c << 12];
      const float xc = xr[w][c];
      a0 = __builtin_fmaf(xc, bf2f((unsigned short)(u & 0xFFFFu)), a0);
      a1 = __builtin_fmaf(xc, bf2f((unsigned short)(u >> 16)), a1);
    }
    const float d0 = __fadd_rn(1.0f, __fmul_rn(-2.0f, a0));
    const float d1 = __fadd_rn(1.0f, __fmul_rn(-2.0f, a1));
    const int k0 = (nb << 7) + (lane << 1);
    if (d0 < thr) {
      const unsigned pos = atomicAdd(&cnt[n], 1u);
      if (pos < (unsigned)CAND_CAP) cand[((size_t)n << 3) + pos] = (unsigned)k0;
    }
    if (d1 < thr) {
      const unsigned pos = atomicAdd(&cnt[n], 1u);
      if (pos < (unsigned)CAND_CAP) cand[((size_t)n << 3) + pos] = (unsigned)(k0 + 1);
    }
    asm volatile("s_waitcnt lgkmcnt(0)" ::: "memory");
  }
}

// =================== exact fp32 refine + insurance ===================
__global__ __launch_bounds__(256) void k_refine(const float* __restrict__ in,
                                                const float* __restrict__ cbk,
                                                const float* __restrict__ a2,
                                                const unsigned* __restrict__ cnt,
                                                const unsigned* __restrict__ cand,
                                                int* __restrict__ idx,
                                                float* __restrict__ idx_f) {
  __shared__ float xrow[4][256];
  const int tid = threadIdx.x;
  const int n0 = blockIdx.x << 2;
  const int b = n0 >> 10, hw0 = n0 & 1023;
  {
    const float4 v = *(const float4*)(in + (((size_t)(b * DIM + tid)) << 10) + hw0);
    xrow[0][tid] = v.x; xrow[1][tid] = v.y; xrow[2][tid] = v.z; xrow[3][tid] = v.w;
  }
  __syncthreads();
  const int w = tid >> 6, lane = tid & 63;
  const int n = n0 + w;
  const unsigned cn = cnt[n];
  const int m = (int)(cn < (unsigned)CAND_CAP ? cn : (unsigned)CAND_CAP);
  unsigned long long key = ~0ull;
  if (lane < m) {
    const unsigned k = cand[((size_t)n << 3) + lane] & 8191u;  // clamp vs poison
    const float* cp = cbk + ((size_t)k << 8);
    float acc = 0.f;
#pragma unroll
    for (int c = 0; c < 256; c += 4) {
      const float4 cv = *(const float4*)(cp + c);
      const float4 xv = *(const float4*)&xrow[w][c];
      acc = __builtin_fmaf(xv.x, cv.x, acc);
      acc = __builtin_fmaf(xv.y, cv.y, acc);
      acc = __builtin_fmaf(xv.z, cv.z, acc);
      acc = __builtin_fmaf(xv.w, cv.w, acc);
    }
    const float d = __fadd_rn(a2[n], __fmul_rn(-2.0f, acc));
    key = ((unsigned long long)__float_as_uint(d) << 32) | (unsigned long long)k;
  }
#pragma unroll
  for (int off = 8; off >= 1; off >>= 1) {
    const unsigned long long o = __shfl_xor(key, off, 64);
    key = (o < key) ? o : key;
  }
  if (lane == 0) {
    const int bi = (int)(key & 0xFFFFFFFFull);
    idx[n] = bi;
    idx_f[n] = (float)bi;
  }
}

// rows with cnt > CAND_CAP: full exact scan
__global__ __launch_bounds__(256) void k_fallback(const float* __restrict__ in,
                                                  const float* __restrict__ cbk,
                                                  const float* __restrict__ a2,
                                                  const unsigned* __restrict__ cnt,
                                                  int* __restrict__ idx,
                                                  float* __restrict__ idx_f) {
  __shared__ float xrow[256];
  __shared__ unsigned long long red[256];
  const int t = threadIdx.x;
  for (int n = blockIdx.x; n < NROWS; n += 512) {
    if (cnt[n] <= (unsigned)CAND_CAP) continue;
    const int b = n >> 10, hw = n & 1023;
    xrow[t] = in[(((size_t)(b * DIM + t)) << 10) + hw];
    __syncthreads();
    unsigned long long key = ~0ull;
    for (int k = t; k < NUM_CODES; k += 256) {
      const float* cp = cbk + ((size_t)k << 8);
      float acc = 0.f;
#pragma unroll
      for (int c = 0; c < 256; c += 4) {
        const float4 cv = *(const float4*)(cp + c);
        acc = __builtin_fmaf(xrow[c + 0], cv.x, acc);
        acc = __builtin_fmaf(xrow[c + 1], cv.y, acc);
        acc = __builtin_fmaf(xrow[c + 2], cv.z, acc);
        acc = __builtin_fmaf(xrow[c + 3], cv.w, acc);
      }
      const float d = __fadd_rn(a2[n], __fmul_rn(-2.0f, acc));
      const unsigned long long kk =
          ((unsigned long long)__float_as_uint(d) << 32) | (unsigned long long)k;
      key = (kk < key) ? kk : key;
    }
    red[t] = key;
    __syncthreads();
    for (int s = 128; s >= 1; s >>= 1) {
      if (t < s) red[t] = (red[t + s] < red[t]) ? red[t + s] : red[t];
      __syncthreads();
    }
    if (t == 0) {
      const int bi = (int)(red[0] & 0xFFFFFFFFull);
      idx[n] = bi;
      idx_f[n] = (float)bi;
    }
    __syncthreads();
  }
}

// =================== legacy path (R4-verified) ===================
__global__ __launch_bounds__(256, 2) void k_argmin_legacy(
    const float* __restrict__ in, const float* __restrict__ cbk,
    const float* __restrict__ a2, int* __restrict__ idx_out,
    float* __restrict__ idx_out_f) {
  __shared__ __align__(16) float xs[32 * 68];
  __shared__ __align__(16) float cs[32 * 260];
  const int tid = threadIdx.x;
  const int trow = tid >> 5;
  const int tcol = tid & 31;
  const int r0 = blockIdx.x << 6;
  const int bb = r0 >> 10;
  const int hw0 = r0 & 1023;
  float ar[8];
#pragma unroll
  for (int r = 0; r < 8; ++r) ar[r] = a2[r0 + (trow << 3) + r];
  float bd[8];
  int bi[8];
#pragma unroll
  for (int r = 0; r < 8; ++r) { bd[r] = 3.402823466e+38f; bi[r] = 0x7fffffff; }
  const int s_ck = tid >> 3;
  const int s_w4 = (tid & 7) << 2;
  for (int kb = 0; kb < NUM_CODES; kb += 256) {
    float acc[8][8];
#pragma unroll
    for (int r = 0; r < 8; ++r)
#pragma unroll
      for (int q = 0; q < 8; ++q) acc[r][q] = 0.f;
    for (int cb = 0; cb < DIM; cb += 32) {
      {
        const float* src = in + (((size_t)(bb * DIM + cb + s_ck)) << 10) + hw0 + s_w4;
        const float4 a = *(const float4*)(src);
        const float4 b = *(const float4*)(src + 32);
        *(float4*)&xs[s_ck * 68 + s_w4] = a;
        *(float4*)&xs[s_ck * 68 + s_w4 + 32] = b;
      }
#pragma unroll
      for (int i = 0; i < 8; ++i) {
        const int fid = tid + (i << 8);
        const int k = fid >> 3;
        const int c4 = (fid & 7) << 2;
        const float4 cv = *(const float4*)(cbk + (((size_t)(kb + k)) << 8) + cb + c4);
        cs[(c4 + 0) * 260 + k] = cv.x;
        cs[(c4 + 1) * 260 + k] = cv.y;
        cs[(c4 + 2) * 260 + k] = cv.z;
        cs[(c4 + 3) * 260 + k] = cv.w;
      }
      __syncthreads();
#pragma unroll 4
      for (int ck = 0; ck < 32; ++ck) {
        const float4 xa = *(const float4*)&xs[ck * 68 + (trow << 3)];
        const float4 xb = *(const float4*)&xs[ck * 68 + (trow << 3) + 4];
        const float4 ca = *(const float4*)&cs[ck * 260 + (tcol << 2)];
        const float4 cb2 = *(const float4*)&cs[ck * 260 + (tcol << 2) + 128];
        const float xv[8] = {xa.x, xa.y, xa.z, xa.w, xb.x, xb.y, xb.z, xb.w};
        const float cv[8] = {ca.x, ca.y, ca.z, ca.w, cb2.x, cb2.y, cb2.z, cb2.w};
#pragma unroll
        for (int r = 0; r < 8; ++r)
#pragma unroll
          for (int q = 0; q < 8; ++q) acc[r][q] = __builtin_fmaf(xv[r], cv[q], acc[r][q]);
      }
      __syncthreads();
    }
#pragma unroll
    for (int g = 0; g < 2; ++g)
#pragma unroll
      for (int j = 0; j < 4; ++j) {
        const int kk = kb + (tcol << 2) + j + (g << 7);
#pragma unroll
        for (int r = 0; r < 8; ++r) {
          const float d = __fadd_rn(ar[r], __fmul_rn(-2.0f, acc[r][(g << 2) + j]));
          if (d < bd[r]) { bd[r] = d; bi[r] = kk; }
        }
      }
  }
  __syncthreads();
  float2* red = (float2*)cs;
#pragma unroll
  for (int r = 0; r < 8; ++r)
    red[((trow << 3) + r) * 32 + tcol] = make_float2(bd[r], __int_as_float(bi[r]));
  __syncthreads();
  if (tid < 64) {
    float bestd = 3.402823466e+38f;
    int besti = 0x7fffffff;
    for (int c = 0; c < 32; ++c) {
      const float2 v = red[tid * 32 + c];
      const int vi = __float_as_int(v.y);
      if (v.x < bestd || (v.x == bestd && vi < besti)) { bestd = v.x; besti = vi; }
    }
    const int n = r0 + tid;
    idx_out[n] = besti;
    idx_out_f[n] = (float)besti;
  }
}

// =================== launch ===================
extern "C" void kernel_launch(void* const* d_in, const int* in_sizes, int n_in,
                              void* d_out, int out_size, void* d_ws, size_t ws_size,
                              hipStream_t stream) {
  const float* in = (const float*)d_in[0];
  const float* cbk = (const float*)d_in[1];
  float* out = (float*)d_out;
  char* ws = (char*)d_ws;

  if (ws_size >= (size_t)WX_END) {
    unsigned short* xt = (unsigned short*)(ws + WX_XT);
    unsigned short* cbb = (unsigned short*)(ws + WX_CBB);
    unsigned short* cbt = (unsigned short*)(ws + WX_CBT);  // aliases bmin
    float* a2 = (float*)(ws + WX_A2);
    float* bmin = (float*)(ws + WX_BMIN);
    float* thrbuf = (float*)(ws + WX_THR);
    unsigned* cnt = (unsigned*)(ws + WX_CNT);
    unsigned* cand = (unsigned*)(ws + WX_CAND);
    unsigned* qcnt = (unsigned*)(ws + WX_QCNT);
    unsigned* queue = (unsigned*)(ws + WX_QUEUE);
    int* idx = (int*)(ws + WX_IDX);          // aliases bmin (dead after k_queue)
    int* counts = (int*)(ws + WX_COUNTS);    // aliases bmin
    double* partials = (double*)(ws + WX_PART);  // aliases bmin

    hipMemsetAsync(cnt, 0, NROWS * sizeof(unsigned), stream);
    hipMemsetAsync(qcnt, 0, sizeof(unsigned), stream);
    k_cvt_cb<<<NUM_CODES * DIM / (256 * 8), 256, 0, stream>>>(cbk, cbb);
    k_cvt_x<<<(NROWS / 64) * 4, 256, 0, stream>>>(in, xt);
    k_a2<<<NROWS / 256, 256, 0, stream>>>(in, a2);
    k_gemm_bmin<<<(NROWS / 128) * (NUM_CODES / 128), 256, 0, stream>>>(xt, cbb, bmin);
    k_queue<<<NROWS / 64, 256, 0, stream>>>(bmin, thrbuf, qcnt, queue, cnt);
    // bmin is dead from here on; its region is reused for cbt/idx/counts/partials
    k_cvt_t<<<(NUM_CODES / 64) * (DIM / 64), 256, 0, stream>>>(cbk, cbt);
    hipMemsetAsync(counts, 0, NUM_CODES * sizeof(int), stream);
    k_dots<<<DOTS_BLOCKS, 256, 0, stream>>>(xt, cbt, thrbuf, qcnt, queue, cnt, cand);
    k_refine<<<NROWS / 4, 256, 0, stream>>>(in, cbk, a2, cnt, cand, idx, out + OUT_IDX);
    k_fallback<<<512, 256, 0, stream>>>(in, cbk, a2, cnt, idx, out + OUT_IDX);
    k_counts<<<NROWS / 256, 256, 0, stream>>>(idx, counts);
    k_quant<<<NELEM / 1024, 256, 0, stream>>>(in, cbk, idx, out + OUT_Q, partials);
    k_finalize<<<1, 256, 0, stream>>>(partials, counts, out + OUT_LOSS, out + OUT_PERP);
  } else {
    // legacy verified path
    float* a2 = (float*)(ws + WL_A2);
    int* idx = (int*)(ws + WL_IDX);
    int* counts = (int*)(ws + WL_COUNTS);
    double* partials = (double*)(ws + WL_PART);
    hipMemsetAsync(counts, 0, NUM_CODES * sizeof(int), stream);
    k_a2<<<NROWS / 256, 256, 0, stream>>>(in, a2);
    k_argmin_legacy<<<NROWS / 64, 256, 0, stream>>>(in, cbk, a2, idx, out + OUT_IDX);
    k_counts<<<NROWS / 256, 256, 0, stream>>>(idx, counts);
    k_quant<<<NELEM / 1024, 256, 0, stream>>>(in, cbk, idx, out + OUT_Q, partials);
    k_finalize<<<1, 256, 0, stream>>>(partials, counts, out + OUT_LOSS, out + OUT_PERP);
  }
}

// Round 8
// 595.132 us; speedup vs baseline: 5.6269x; 1.6253x over previous
//
#include <hip/hip_runtime.h>
#include <math.h>

#define NUM_CODES 8192
#define DIM 256
#define NROWS 32768            // 32 * 32 * 32
#define NELEM (NROWS * DIM)    // 8388608

// d_out layout (fp32 elements): loss | quantized | perplexity | indices
#define OUT_LOSS 0
#define OUT_Q 1
#define OUT_PERP (1 + NELEM)
#define OUT_IDX (2 + NELEM)

#define DELTA 2e-4f
#define CAND_CAP 8
#define QCAP 262144
#define BLKQ 512
#define DOTS_BLOCKS 2048
#define NQBLK (NELEM / 1024)

// ---- ws layout (bytes); END fits under the PROVEN 31.97 MB bound ----
#define WX_XT    0x0        // 32768*256 bf16 (16 MB)
#define WX_CBB   0x1000000  // 8192*256 bf16 (4 MB)
#define WX_A2    0x1400000  // 32768 f32 (128 KB)
#define WX_BMIN  0x1420000  // 64*32768 f32 (8 MB) -- dead after k_queue; aliased:
#define WX_CBT   (WX_BMIN)              // 8192*256 bf16 transposed (4 MB)
#define WX_IDX   (WX_BMIN + 0x400000)   // 32768 i32
#define WX_COUNTS (WX_BMIN + 0x420000)  // 8192 i32
#define WX_PART  (WX_BMIN + 0x428000)   // 8192 f64
#define WX_THR   0x1C20000  // 32768 f32 (128 KB)
#define WX_CNT   0x1C40000  // 32768 u32 (128 KB)
#define WX_CAND  0x1C60000  // 32768*8 u32 (1 MB)
#define WX_QCNT  0x1D60000  // 4 KB
#define WX_QUEUE 0x1D61000  // 262144 u32 (1 MB)
#define WX_END   0x1E61000  // 31.85 MB < proven 31.97 MB

// ---- legacy (R4-verified) ws layout ----
#define WL_A2 0
#define WL_IDX 0x20000
#define WL_COUNTS 0x40000
#define WL_PART 0x48000

typedef __bf16 bf16x8 __attribute__((ext_vector_type(8)));
typedef float f32x4 __attribute__((ext_vector_type(4)));

__device__ __forceinline__ unsigned f2bf_rne(float x) {
  const unsigned u = __float_as_uint(x);
  return (u + 0x7FFFu + ((u >> 16) & 1u)) >> 16;
}
__device__ __forceinline__ float bf2f(unsigned short h) {
  return __uint_as_float((unsigned)h << 16);
}

// =================== shared kernels ===================

// A[n] = np.sum(flat[n]**2), exact numpy pairwise fp32 (verified R3-R7)
__global__ __launch_bounds__(256) void k_a2(const float* __restrict__ in,
                                            float* __restrict__ a2) {
  const int n = (blockIdx.x << 8) + threadIdx.x;
  const int b = n >> 10, hw = n & 1023;
  const float* p = in + (((size_t)b) << 18) + hw;
  float s[2];
#pragma unroll
  for (int h = 0; h < 2; ++h) {
    const int c0 = h << 7;
    float r[8];
#pragma unroll
    for (int j = 0; j < 8; ++j) {
      const float v = p[(size_t)(c0 + j) << 10];
      r[j] = __fmul_rn(v, v);
    }
    for (int i = 8; i < 128; i += 8) {
#pragma unroll
      for (int j = 0; j < 8; ++j) {
        const float v = p[(size_t)(c0 + i + j) << 10];
        r[j] = __fadd_rn(r[j], __fmul_rn(v, v));
      }
    }
    s[h] = __fadd_rn(__fadd_rn(__fadd_rn(r[0], r[1]), __fadd_rn(r[2], r[3])),
                     __fadd_rn(__fadd_rn(r[4], r[5]), __fadd_rn(r[6], r[7])));
  }
  a2[n] = __fadd_rn(s[0], s[1]);
}

__global__ __launch_bounds__(256) void k_cvt_cb(const float* __restrict__ cbk,
                                                unsigned short* __restrict__ cbb) {
  const int e = (((blockIdx.x << 8) + threadIdx.x) << 3);
  const float4 a = *(const float4*)(cbk + e);
  const float4 b = *(const float4*)(cbk + e + 4);
  uint4 o;
  o.x = f2bf_rne(a.x) | (f2bf_rne(a.y) << 16);
  o.y = f2bf_rne(a.z) | (f2bf_rne(a.w) << 16);
  o.z = f2bf_rne(b.x) | (f2bf_rne(b.y) << 16);
  o.w = f2bf_rne(b.z) | (f2bf_rne(b.w) << 16);
  *(uint4*)(cbb + e) = o;
}

__global__ __launch_bounds__(256) void k_cvt_x(const float* __restrict__ in,
                                               unsigned short* __restrict__ xt) {
  __shared__ float t[64][65];
  const int tid = threadIdx.x;
  const int n0 = (blockIdx.x >> 2) << 6;
  const int c0 = (blockIdx.x & 3) << 6;
  const int b = n0 >> 10, hw0 = n0 & 1023;
#pragma unroll
  for (int i = 0; i < 4; ++i) {
    const int f = (i << 8) + tid;
    const int cl = f >> 4;
    const int h4 = (f & 15) << 2;
    const float4 v = *(const float4*)(in + (((size_t)(b * DIM + c0 + cl)) << 10) + hw0 + h4);
    t[cl][h4 + 0] = v.x;
    t[cl][h4 + 1] = v.y;
    t[cl][h4 + 2] = v.z;
    t[cl][h4 + 3] = v.w;
  }
  __syncthreads();
#pragma unroll
  for (int i = 0; i < 2; ++i) {
    const int f = (i << 8) + tid;
    const int nl = f >> 3;
    const int c8 = (f & 7) << 3;
    uint4 o;
    o.x = f2bf_rne(t[c8 + 0][nl]) | (f2bf_rne(t[c8 + 1][nl]) << 16);
    o.y = f2bf_rne(t[c8 + 2][nl]) | (f2bf_rne(t[c8 + 3][nl]) << 16);
    o.z = f2bf_rne(t[c8 + 4][nl]) | (f2bf_rne(t[c8 + 5][nl]) << 16);
    o.w = f2bf_rne(t[c8 + 6][nl]) | (f2bf_rne(t[c8 + 7][nl]) << 16);
    *(uint4*)&xt[(((size_t)(n0 + nl)) << 8) + c0 + c8] = o;
  }
}

// codebook fp32 [k][c] -> TRANSPOSED bf16 cbt[c][k] (same RNE values as cbb)
__global__ __launch_bounds__(256) void k_cvt_t(const float* __restrict__ cbk,
                                               unsigned short* __restrict__ cbt) {
  __shared__ unsigned short tl[64][68];
  const int tid = threadIdx.x;
  const int kb = (blockIdx.x >> 2) << 6;
  const int cb = (blockIdx.x & 3) << 6;
#pragma unroll
  for (int i = 0; i < 4; ++i) {
    const int f = (i << 8) + tid;
    const int kl = f >> 4;
    const int c4 = (f & 15) << 2;
    const float4 v = *(const float4*)(cbk + ((size_t)(kb + kl) << 8) + cb + c4);
    tl[kl][c4 + 0] = (unsigned short)f2bf_rne(v.x);
    tl[kl][c4 + 1] = (unsigned short)f2bf_rne(v.y);
    tl[kl][c4 + 2] = (unsigned short)f2bf_rne(v.z);
    tl[kl][c4 + 3] = (unsigned short)f2bf_rne(v.w);
  }
  __syncthreads();
#pragma unroll
  for (int i = 0; i < 4; ++i) {
    const int f = (i << 8) + tid;
    const int cl = f >> 4;
    const int k4 = (f & 15) << 2;
    ushort4 o;
    o.x = tl[k4 + 0][cl];
    o.y = tl[k4 + 1][cl];
    o.z = tl[k4 + 2][cl];
    o.w = tl[k4 + 3][cl];
    *(ushort4*)&cbt[((size_t)(cb + cl) << 13) + kb + k4] = o;
  }
}

__global__ __launch_bounds__(256) void k_quant(const float* __restrict__ in,
                                               const float* __restrict__ cbk,
                                               const int* __restrict__ idx,
                                               float* __restrict__ outq,
                                               double* __restrict__ partials) {
  const int tid = threadIdx.x;
  const int e = (blockIdx.x << 10) + (tid << 2);
  const int bc = e >> 10;
  const int hw = e & 1023;
  const int b = bc >> 8;
  const int c = bc & 255;
  const int nbase = (b << 10) + hw;
  const float4 x = *(const float4*)(in + e);
  const float xv[4] = {x.x, x.y, x.z, x.w};
  double ls = 0.0;
  float o[4];
#pragma unroll
  for (int j = 0; j < 4; ++j) {
    const int qi = idx[nbase + j];
    const float q = cbk[((size_t)qi << 8) + c];
    const float diff = q - xv[j];
    o[j] = xv[j] + diff;
    ls += (double)diff * (double)diff;
  }
  outq[e] = o[0];
  outq[e + 1] = o[1];
  outq[e + 2] = o[2];
  outq[e + 3] = o[3];
#pragma unroll
  for (int off = 32; off >= 1; off >>= 1) ls += __shfl_down(ls, off, 64);
  __shared__ double wsum[4];
  const int lane = tid & 63, wid = tid >> 6;
  if (lane == 0) wsum[wid] = ls;
  __syncthreads();
  if (tid == 0) partials[blockIdx.x] = wsum[0] + wsum[1] + wsum[2] + wsum[3];
}

__global__ __launch_bounds__(256) void k_counts(const int* __restrict__ idx,
                                                int* __restrict__ counts) {
  const int n = (blockIdx.x << 8) + threadIdx.x;
  atomicAdd(&counts[idx[n]], 1);
}

__global__ __launch_bounds__(256) void k_finalize(const double* __restrict__ partials,
                                                  const int* __restrict__ counts,
                                                  float* __restrict__ out_loss,
                                                  float* __restrict__ out_perp) {
  const int tid = threadIdx.x;
  double sl = 0.0, se = 0.0;
  for (int i = tid; i < NQBLK; i += 256) sl += partials[i];
  for (int k = tid; k < NUM_CODES; k += 256) {
    const double p = (double)counts[k] / 32768.0;
    se += p * log(p + 1e-10);
  }
#pragma unroll
  for (int off = 32; off >= 1; off >>= 1) {
    sl += __shfl_down(sl, off, 64);
    se += __shfl_down(se, off, 64);
  }
  __shared__ double sL[4], sE[4];
  const int lane = tid & 63, wid = tid >> 6;
  if (lane == 0) { sL[wid] = sl; sE[wid] = se; }
  __syncthreads();
  if (tid == 0) {
    const double L = sL[0] + sL[1] + sL[2] + sL[3];
    const double E = sE[0] + sE[1] + sE[2] + sE[3];
    const double m = L / (double)NELEM;
    *out_loss = (float)(m + 0.6 * m);
    *out_perp = (float)exp(-E);
  }
}

// =================== MFMA screen GEMM (R6-verified) ===================
// 128 rows x 128 codes per block, K=256 in 64-chunks. d~ = fl(1 - 2*G^).
// Writes per-(row, 128-code-block) min to bmin[nb][row].
#define XS_STR 72
__global__ __launch_bounds__(256, 4) void k_gemm_bmin(
    const unsigned short* __restrict__ xt, const unsigned short* __restrict__ cbb,
    float* __restrict__ bmin) {
  __shared__ __align__(16) unsigned short xs[128 * XS_STR];
  __shared__ __align__(16) unsigned short cs[128 * XS_STR];
  const int tid = threadIdx.x;
  const int lane = tid & 63;
  const int w = tid >> 6;
  const int wm = w >> 1, wn = w & 1;
  const int m0 = (blockIdx.x >> 6) << 7;
  const int nb = blockIdx.x & 63;
  const int n0 = nb << 7;
  const int quad = lane >> 4;
  const int l15 = lane & 15;

  f32x4 acc[4][4];
#pragma unroll
  for (int mt = 0; mt < 4; ++mt)
#pragma unroll
    for (int nt = 0; nt < 4; ++nt) acc[mt][nt] = (f32x4){0.f, 0.f, 0.f, 0.f};

  for (int ch0 = 0; ch0 < DIM; ch0 += 64) {
#pragma unroll
    for (int i = 0; i < 4; ++i) {
      const int f = (i << 8) + tid;
      const int row = f >> 3;
      const int k8 = (f & 7) << 3;
      *(uint4*)&xs[row * XS_STR + k8] = *(const uint4*)&xt[((m0 + row) << 8) + ch0 + k8];
      *(uint4*)&cs[row * XS_STR + k8] = *(const uint4*)&cbb[((n0 + row) << 8) + ch0 + k8];
    }
    __syncthreads();
#pragma unroll
    for (int ks = 0; ks < 2; ++ks) {
      bf16x8 af[4], bf_[4];
#pragma unroll
      for (int mt = 0; mt < 4; ++mt)
        af[mt] = *(const bf16x8*)&xs[((wm << 6) + (mt << 4) + l15) * XS_STR + (ks << 5) + (quad << 3)];
#pragma unroll
      for (int nt = 0; nt < 4; ++nt)
        bf_[nt] = *(const bf16x8*)&cs[((wn << 6) + (nt << 4) + l15) * XS_STR + (ks << 5) + (quad << 3)];
#pragma unroll
      for (int mt = 0; mt < 4; ++mt)
#pragma unroll
        for (int nt = 0; nt < 4; ++nt)
          acc[mt][nt] = __builtin_amdgcn_mfma_f32_16x16x32_bf16(af[mt], bf_[nt], acc[mt][nt], 0, 0, 0);
    }
    __syncthreads();
  }

  float* sred = (float*)cs;  // [2][128]
#pragma unroll
  for (int mt = 0; mt < 4; ++mt)
#pragma unroll
    for (int reg = 0; reg < 4; ++reg) {
      float v = 3.402823466e+38f;
#pragma unroll
      for (int nt = 0; nt < 4; ++nt) {
        const float d = __fadd_rn(1.0f, __fmul_rn(-2.0f, acc[mt][nt][reg]));
        v = fminf(v, d);
      }
      v = fminf(v, __shfl_xor(v, 1, 64));
      v = fminf(v, __shfl_xor(v, 2, 64));
      v = fminf(v, __shfl_xor(v, 4, 64));
      v = fminf(v, __shfl_xor(v, 8, 64));
      if (l15 == 0)
        sred[(wn << 7) + (wm << 6) + (mt << 4) + (quad << 2) + reg] = v;
    }
  __syncthreads();
  if (tid < 128)
    bmin[(size_t)nb * NROWS + m0 + tid] = fminf(sred[tid], sred[128 + tid]);
}

// =================== candidate pipeline ===================

// per 64-row block: per-row global min + thr; push qualifying (row, nb) pairs.
// Block-aggregated queue: LDS-local list, ONE global atomicAdd per block.
__global__ __launch_bounds__(256) void k_queue(const float* __restrict__ bmin,
                                               float* __restrict__ thrbuf,
                                               unsigned* __restrict__ qcnt,
                                               unsigned* __restrict__ queue,
                                               unsigned* __restrict__ cnt) {
  __shared__ float bmt[64 * 65];
  __shared__ unsigned lq[BLKQ];
  __shared__ unsigned lcnt, gbase;
  const int tid = threadIdx.x, w = tid >> 6, lane = tid & 63;
  const int r0 = blockIdx.x << 6;
  if (tid == 0) lcnt = 0;
#pragma unroll
  for (int i = 0; i < 16; ++i) {
    const int nb = (i << 2) + w;
    bmt[nb * 65 + lane] = bmin[(size_t)nb * NROWS + r0 + lane];
  }
  __syncthreads();
  for (int j = 0; j < 16; ++j) {
    const int rloc = (w << 4) + j;
    const int n = r0 + rloc;
    const float v = bmt[lane * 65 + rloc];
    float g = v;
    g = fminf(g, __shfl_xor(g, 32, 64));
    g = fminf(g, __shfl_xor(g, 16, 64));
    g = fminf(g, __shfl_xor(g, 8, 64));
    g = fminf(g, __shfl_xor(g, 4, 64));
    g = fminf(g, __shfl_xor(g, 2, 64));
    g = fminf(g, __shfl_xor(g, 1, 64));
    const float thr = g + DELTA;
    if (lane == 0) thrbuf[n] = thr;
    if (v <= thr) {
      const unsigned pos = atomicAdd(&lcnt, 1u);
      if (pos < (unsigned)BLKQ) lq[pos] = ((unsigned)n << 6) | (unsigned)lane;
      else atomicAdd(&cnt[n], 64u);  // local overflow -> exact fallback row
    }
  }
  __syncthreads();
  const unsigned tot = (lcnt < (unsigned)BLKQ) ? lcnt : (unsigned)BLKQ;
  if (tid == 0) gbase = atomicAdd(qcnt, tot);
  __syncthreads();
  const unsigned base = gbase;
  for (unsigned i = tid; i < tot; i += 256) {
    const unsigned pos = base + i;
    const unsigned pr = lq[i];
    if (pos < (unsigned)QCAP) queue[pos] = pr;
    else atomicAdd(&cnt[pr >> 6], 64u);  // global overflow -> exact fallback row
  }
}

// one wave per queued (row, nb) pair: 2 codes/lane, coalesced cbt loads
__global__ __launch_bounds__(256) void k_dots(const unsigned short* __restrict__ xt,
                                              const unsigned short* __restrict__ cbt,
                                              const float* __restrict__ thrbuf,
                                              const unsigned* __restrict__ qcnt,
                                              const unsigned* __restrict__ queue,
                                              unsigned* __restrict__ cnt,
                                              unsigned* __restrict__ cand) {
  __shared__ float xr[4][256];
  const int tid = threadIdx.x, w = tid >> 6, lane = tid & 63;
  const unsigned qv = *qcnt;
  const int qn = (int)(qv < (unsigned)QCAP ? qv : (unsigned)QCAP);
  const unsigned* c32 = (const unsigned*)cbt;  // [c][k/2] u32 pairs
  for (int p = (blockIdx.x << 2) + w; p < qn; p += (DOTS_BLOCKS << 2)) {
    const unsigned pr = queue[p];
    const int n = (int)(pr >> 6), nb = (int)(pr & 63u);
    {
      const ushort4 hv = *(const ushort4*)&xt[((size_t)n << 8) + (lane << 2)];
      xr[w][(lane << 2) + 0] = bf2f(hv.x);
      xr[w][(lane << 2) + 1] = bf2f(hv.y);
      xr[w][(lane << 2) + 2] = bf2f(hv.z);
      xr[w][(lane << 2) + 3] = bf2f(hv.w);
    }
    asm volatile("s_waitcnt lgkmcnt(0)" ::: "memory");  // wave-local LDS visibility
    const float thr = thrbuf[n];
    const unsigned* cp = c32 + (nb << 6) + lane;
    float a0 = 0.f, a1 = 0.f;
#pragma unroll 8
    for (int c = 0; c < 256; ++c) {
      const unsigned u = cp[c << 12];
      const float xc = xr[w][c];
      a0 = __builtin_fmaf(xc, bf2f((unsigned short)(u & 0xFFFFu)), a0);
      a1 = __builtin_fmaf(xc, bf2f((unsigned short)(u >> 16)), a1);
    }
    const float d0 = __fadd_rn(1.0f, __fmul_rn(-2.0f, a0));
    const float d1 = __fadd_rn(1.0f, __fmul_rn(-2.0f, a1));
    const int k0 = (nb << 7) + (lane << 1);
    if (d0 < thr) {
      const unsigned pos = atomicAdd(&cnt[n], 1u);
      if (pos < (unsigned)CAND_CAP) cand[((size_t)n << 3) + pos] = (unsigned)k0;
    }
    if (d1 < thr) {
      const unsigned pos = atomicAdd(&cnt[n], 1u);
      if (pos < (unsigned)CAND_CAP) cand[((size_t)n << 3) + pos] = (unsigned)(k0 + 1);
    }
    asm volatile("s_waitcnt lgkmcnt(0)" ::: "memory");
  }
}

// =================== exact fp32 refine + insurance ===================
__global__ __launch_bounds__(256) void k_refine(const float* __restrict__ in,
                                                const float* __restrict__ cbk,
                                                const float* __restrict__ a2,
                                                const unsigned* __restrict__ cnt,
                                                const unsigned* __restrict__ cand,
                                                int* __restrict__ idx,
                                                float* __restrict__ idx_f) {
  __shared__ float xrow[4][256];
  const int tid = threadIdx.x;
  const int n0 = blockIdx.x << 2;
  const int b = n0 >> 10, hw0 = n0 & 1023;
  {
    const float4 v = *(const float4*)(in + (((size_t)(b * DIM + tid)) << 10) + hw0);
    xrow[0][tid] = v.x; xrow[1][tid] = v.y; xrow[2][tid] = v.z; xrow[3][tid] = v.w;
  }
  __syncthreads();
  const int w = tid >> 6, lane = tid & 63;
  const int n = n0 + w;
  const unsigned cn = cnt[n];
  const int m = (int)(cn < (unsigned)CAND_CAP ? cn : (unsigned)CAND_CAP);
  unsigned long long key = ~0ull;
  if (lane < m) {
    const unsigned k = cand[((size_t)n << 3) + lane] & 8191u;  // clamp vs poison
    const float* cp = cbk + ((size_t)k << 8);
    float acc = 0.f;
#pragma unroll
    for (int c = 0; c < 256; c += 4) {
      const float4 cv = *(const float4*)(cp + c);
      const float4 xv = *(const float4*)&xrow[w][c];
      acc = __builtin_fmaf(xv.x, cv.x, acc);
      acc = __builtin_fmaf(xv.y, cv.y, acc);
      acc = __builtin_fmaf(xv.z, cv.z, acc);
      acc = __builtin_fmaf(xv.w, cv.w, acc);
    }
    const float d = __fadd_rn(a2[n], __fmul_rn(-2.0f, acc));
    key = ((unsigned long long)__float_as_uint(d) << 32) | (unsigned long long)k;
  }
#pragma unroll
  for (int off = 8; off >= 1; off >>= 1) {
    const unsigned long long o = __shfl_xor(key, off, 64);
    key = (o < key) ? o : key;
  }
  if (lane == 0) {
    const int bi = (int)(key & 0xFFFFFFFFull);
    idx[n] = bi;
    idx_f[n] = (float)bi;
  }
}

// rows with cnt > CAND_CAP: full exact scan
__global__ __launch_bounds__(256) void k_fallback(const float* __restrict__ in,
                                                  const float* __restrict__ cbk,
                                                  const float* __restrict__ a2,
                                                  const unsigned* __restrict__ cnt,
                                                  int* __restrict__ idx,
                                                  float* __restrict__ idx_f) {
  __shared__ float xrow[256];
  __shared__ unsigned long long red[256];
  const int t = threadIdx.x;
  for (int n = blockIdx.x; n < NROWS; n += 512) {
    if (cnt[n] <= (unsigned)CAND_CAP) continue;
    const int b = n >> 10, hw = n & 1023;
    xrow[t] = in[(((size_t)(b * DIM + t)) << 10) + hw];
    __syncthreads();
    unsigned long long key = ~0ull;
    for (int k = t; k < NUM_CODES; k += 256) {
      const float* cp = cbk + ((size_t)k << 8);
      float acc = 0.f;
#pragma unroll
      for (int c = 0; c < 256; c += 4) {
        const float4 cv = *(const float4*)(cp + c);
        acc = __builtin_fmaf(xrow[c + 0], cv.x, acc);
        acc = __builtin_fmaf(xrow[c + 1], cv.y, acc);
        acc = __builtin_fmaf(xrow[c + 2], cv.z, acc);
        acc = __builtin_fmaf(xrow[c + 3], cv.w, acc);
      }
      const float d = __fadd_rn(a2[n], __fmul_rn(-2.0f, acc));
      const unsigned long long kk =
          ((unsigned long long)__float_as_uint(d) << 32) | (unsigned long long)k;
      key = (kk < key) ? kk : key;
    }
    red[t] = key;
    __syncthreads();
    for (int s = 128; s >= 1; s >>= 1) {
      if (t < s) red[t] = (red[t + s] < red[t]) ? red[t + s] : red[t];
      __syncthreads();
    }
    if (t == 0) {
      const int bi = (int)(red[0] & 0xFFFFFFFFull);
      idx[n] = bi;
      idx_f[n] = (float)bi;
    }
    __syncthreads();
  }
}

// =================== legacy path (R4-verified) ===================
__global__ __launch_bounds__(256, 2) void k_argmin_legacy(
    const float* __restrict__ in, const float* __restrict__ cbk,
    const float* __restrict__ a2, int* __restrict__ idx_out,
    float* __restrict__ idx_out_f) {
  __shared__ __align__(16) float xs[32 * 68];
  __shared__ __align__(16) float cs[32 * 260];
  const int tid = threadIdx.x;
  const int trow = tid >> 5;
  const int tcol = tid & 31;
  const int r0 = blockIdx.x << 6;
  const int bb = r0 >> 10;
  const int hw0 = r0 & 1023;
  float ar[8];
#pragma unroll
  for (int r = 0; r < 8; ++r) ar[r] = a2[r0 + (trow << 3) + r];
  float bd[8];
  int bi[8];
#pragma unroll
  for (int r = 0; r < 8; ++r) { bd[r] = 3.402823466e+38f; bi[r] = 0x7fffffff; }
  const int s_ck = tid >> 3;
  const int s_w4 = (tid & 7) << 2;
  for (int kb = 0; kb < NUM_CODES; kb += 256) {
    float acc[8][8];
#pragma unroll
    for (int r = 0; r < 8; ++r)
#pragma unroll
      for (int q = 0; q < 8; ++q) acc[r][q] = 0.f;
    for (int cb = 0; cb < DIM; cb += 32) {
      {
        const float* src = in + (((size_t)(bb * DIM + cb + s_ck)) << 10) + hw0 + s_w4;
        const float4 a = *(const float4*)(src);
        const float4 b = *(const float4*)(src + 32);
        *(float4*)&xs[s_ck * 68 + s_w4] = a;
        *(float4*)&xs[s_ck * 68 + s_w4 + 32] = b;
      }
#pragma unroll
      for (int i = 0; i < 8; ++i) {
        const int fid = tid + (i << 8);
        const int k = fid >> 3;
        const int c4 = (fid & 7) << 2;
        const float4 cv = *(const float4*)(cbk + (((size_t)(kb + k)) << 8) + cb + c4);
        cs[(c4 + 0) * 260 + k] = cv.x;
        cs[(c4 + 1) * 260 + k] = cv.y;
        cs[(c4 + 2) * 260 + k] = cv.z;
        cs[(c4 + 3) * 260 + k] = cv.w;
      }
      __syncthreads();
#pragma unroll 4
      for (int ck = 0; ck < 32; ++ck) {
        const float4 xa = *(const float4*)&xs[ck * 68 + (trow << 3)];
        const float4 xb = *(const float4*)&xs[ck * 68 + (trow << 3) + 4];
        const float4 ca = *(const float4*)&cs[ck * 260 + (tcol << 2)];
        const float4 cb2 = *(const float4*)&cs[ck * 260 + (tcol << 2) + 128];
        const float xv[8] = {xa.x, xa.y, xa.z, xa.w, xb.x, xb.y, xb.z, xb.w};
        const float cv[8] = {ca.x, ca.y, ca.z, ca.w, cb2.x, cb2.y, cb2.z, cb2.w};
#pragma unroll
        for (int r = 0; r < 8; ++r)
#pragma unroll
          for (int q = 0; q < 8; ++q) acc[r][q] = __builtin_fmaf(xv[r], cv[q], acc[r][q]);
      }
      __syncthreads();
    }
#pragma unroll
    for (int g = 0; g < 2; ++g)
#pragma unroll
      for (int j = 0; j < 4; ++j) {
        const int kk = kb + (tcol << 2) + j + (g << 7);
#pragma unroll
        for (int r = 0; r < 8; ++r) {
          const float d = __fadd_rn(ar[r], __fmul_rn(-2.0f, acc[r][(g << 2) + j]));
          if (d < bd[r]) { bd[r] = d; bi[r] = kk; }
        }
      }
  }
  __syncthreads();
  float2* red = (float2*)cs;
#pragma unroll
  for (int r = 0; r < 8; ++r)
    red[((trow << 3) + r) * 32 + tcol] = make_float2(bd[r], __int_as_float(bi[r]));
  __syncthreads();
  if (tid < 64) {
    float bestd = 3.402823466e+38f;
    int besti = 0x7fffffff;
    for (int c = 0; c < 32; ++c) {
      const float2 v = red[tid * 32 + c];
      const int vi = __float_as_int(v.y);
      if (v.x < bestd || (v.x == bestd && vi < besti)) { bestd = v.x; besti = vi; }
    }
    const int n = r0 + tid;
    idx_out[n] = besti;
    idx_out_f[n] = (float)besti;
  }
}

// =================== launch ===================
extern "C" void kernel_launch(void* const* d_in, const int* in_sizes, int n_in,
                              void* d_out, int out_size, void* d_ws, size_t ws_size,
                              hipStream_t stream) {
  const float* in = (const float*)d_in[0];
  const float* cbk = (const float*)d_in[1];
  float* out = (float*)d_out;
  char* ws = (char*)d_ws;

  if (ws_size >= (size_t)WX_END) {
    unsigned short* xt = (unsigned short*)(ws + WX_XT);
    unsigned short* cbb = (unsigned short*)(ws + WX_CBB);
    unsigned short* cbt = (unsigned short*)(ws + WX_CBT);  // aliases bmin
    float* a2 = (float*)(ws + WX_A2);
    float* bmin = (float*)(ws + WX_BMIN);
    float* thrbuf = (float*)(ws + WX_THR);
    unsigned* cnt = (unsigned*)(ws + WX_CNT);
    unsigned* cand = (unsigned*)(ws + WX_CAND);
    unsigned* qcnt = (unsigned*)(ws + WX_QCNT);
    unsigned* queue = (unsigned*)(ws + WX_QUEUE);
    int* idx = (int*)(ws + WX_IDX);          // aliases bmin (dead after k_queue)
    int* counts = (int*)(ws + WX_COUNTS);    // aliases bmin
    double* partials = (double*)(ws + WX_PART);  // aliases bmin

    hipMemsetAsync(cnt, 0, NROWS * sizeof(unsigned), stream);
    hipMemsetAsync(qcnt, 0, sizeof(unsigned), stream);
    k_cvt_cb<<<NUM_CODES * DIM / (256 * 8), 256, 0, stream>>>(cbk, cbb);
    k_cvt_x<<<(NROWS / 64) * 4, 256, 0, stream>>>(in, xt);
    k_a2<<<NROWS / 256, 256, 0, stream>>>(in, a2);
    k_gemm_bmin<<<(NROWS / 128) * (NUM_CODES / 128), 256, 0, stream>>>(xt, cbb, bmin);
    k_queue<<<NROWS / 64, 256, 0, stream>>>(bmin, thrbuf, qcnt, queue, cnt);
    // bmin is dead from here on; its region is reused for cbt/idx/counts/partials
    k_cvt_t<<<(NUM_CODES / 64) * (DIM / 64), 256, 0, stream>>>(cbk, cbt);
    hipMemsetAsync(counts, 0, NUM_CODES * sizeof(int), stream);
    k_dots<<<DOTS_BLOCKS, 256, 0, stream>>>(xt, cbt, thrbuf, qcnt, queue, cnt, cand);
    k_refine<<<NROWS / 4, 256, 0, stream>>>(in, cbk, a2, cnt, cand, idx, out + OUT_IDX);
    k_fallback<<<512, 256, 0, stream>>>(in, cbk, a2, cnt, idx, out + OUT_IDX);
    k_counts<<<NROWS / 256, 256, 0, stream>>>(idx, counts);
    k_quant<<<NELEM / 1024, 256, 0, stream>>>(in, cbk, idx, out + OUT_Q, partials);
    k_finalize<<<1, 256, 0, stream>>>(partials, counts, out + OUT_LOSS, out + OUT_PERP);
  } else {
    // legacy verified path
    float* a2 = (float*)(ws + WL_A2);
    int* idx = (int*)(ws + WL_IDX);
    int* counts = (int*)(ws + WL_COUNTS);
    double* partials = (double*)(ws + WL_PART);
    hipMemsetAsync(counts, 0, NUM_CODES * sizeof(int), stream);
    k_a2<<<NROWS / 256, 256, 0, stream>>>(in, a2);
    k_argmin_legacy<<<NROWS / 64, 256, 0, stream>>>(in, cbk, a2, idx, out + OUT_IDX);
    k_counts<<<NROWS / 256, 256, 0, stream>>>(idx, counts);
    k_quant<<<NELEM / 1024, 256, 0, stream>>>(in, cbk, idx, out + OUT_Q, partials);
    k_finalize<<<1, 256, 0, stream>>>(partials, counts, out + OUT_LOSS, out + OUT_PERP);
  }
}